// Round 9
// baseline (510.817 us; speedup 1.0000x reference)
//
#include <hip/hip_runtime.h>
#include <hip/hip_bf16.h>
#include <hip/hip_fp16.h>

#define N_NODES 100000
#define N_EDGES 1600000
#define ETOT    (N_EDGES + N_NODES)   // 1,700,000
#define NE3     (3 * ETOT)            // 5,100,000
#define N3      (3 * N_NODES)         // 300,000
#define NF      256
#define NG      512
#define NHC     64
#define NOUT3   192
#define BN_EPS  1e-5f

// bucket sort params: 512-node buckets
#define NBUCK   586                   // ceil(300000/512)
#define NB1     1024                  // level-1 blocks
#define EGRAIN  20
#define ECHUNK  (256 * EGRAIN)        // 5120
#define SCAN_N  (NBUCK * NB1)         // 600064
#define ATT2_NB (N_NODES * 16 / 256)  // 6250

typedef _Float16 f16x8 __attribute__((ext_vector_type(8)));
typedef float    f32x4 __attribute__((ext_vector_type(4)));

__device__ __forceinline__ unsigned fenc(float f){
  unsigned b = __float_as_uint(f);
  return (b & 0x80000000u) ? ~b : (b | 0x80000000u);
}
__device__ __forceinline__ float fdec(unsigned u){
  unsigned b = (u & 0x80000000u) ? (u & 0x7FFFFFFFu) : ~u;
  return __uint_as_float(b);
}
__device__ __forceinline__ float lrelu(float x){ return x > 0.f ? x : 0.2f * x; }
__device__ __forceinline__ float eluf(float x){ return x > 0.f ? x : (__expf(x) - 1.f); }

// ---------------- init pooled to encoded -inf ----------------
__global__ void k_init_pooled(unsigned* pooled){
  int i = blockIdx.x * 256 + threadIdx.x;
  if (i < 3 * NG * NHC) pooled[i] = 0x007FFFFFu;   // fenc(-inf)
}

// ---------------- fused: column stats of x + level-1 edge histogram ----------------
#define STATS_NB ((N_NODES + 127) / 128)    // 782
__global__ __launch_bounds__(256) void k_pre(const float* __restrict__ x,
                                             float* __restrict__ sums, float* __restrict__ sumsq,
                                             const int* __restrict__ eA, const int* __restrict__ eC,
                                             const int* __restrict__ eP,
                                             int* __restrict__ gcounts){
  int t = threadIdx.x;
  if (blockIdx.x < STATS_NB){
    int r0 = blockIdx.x * 128;
    int rmax = N_NODES - r0; if (rmax > 128) rmax = 128;
    float s = 0.f, q = 0.f;
    for (int r = 0; r < rmax; ++r){
      float v = x[(size_t)(r0 + r) * NF + t];
      s += v; q += v * v;
    }
    atomicAdd(&sums[t], s);
    atomicAdd(&sumsq[t], q);
    return;
  }
  __shared__ int hist[NBUCK];
  int bi = blockIdx.x - STATS_NB;
  for (int b = t; b < NBUCK; b += 256) hist[b] = 0;
  __syncthreads();
  int base = bi * ECHUNK + t;
#pragma unroll
  for (int k = 0; k < EGRAIN; ++k){
    int i = base + k * 256;
    if (i < NE3){
      int v = i / ETOT; int j = i - v * ETOT;
      const int* ei = (v == 0) ? eA : (v == 1) ? eC : eP;
      int d = (j < N_EDGES) ? ei[N_EDGES + j] : (j - N_EDGES);
      int vd = v * N_NODES + d;
      atomicAdd(&hist[vd >> 9], 1);
    }
  }
  __syncthreads();
  for (int b = t; b < NBUCK; b += 256) gcounts[b * NB1 + bi] = hist[b];
}

// ---------------- fold BN into W'^T (fp16, [192][256]) and bias b' ----------------
__global__ __launch_bounds__(256) void k_prep2(const float* __restrict__ sums, const float* __restrict__ sumsq,
                                               const float* __restrict__ bn_w, const float* __restrict__ bn_b,
                                               const float* __restrict__ WA, const float* __restrict__ WC,
                                               const float* __restrict__ WP,
                                               __half* __restrict__ WpT, float* __restrict__ bp){
  __shared__ float red[256];
  int o = blockIdx.x;                 // 0..191
  int v = o >> 6, oc = o & 63;
  const float* W = (v == 0) ? WA : (v == 1) ? WC : WP;
  int f = threadIdx.x;
  float mu  = sums[f]  * (1.f / N_NODES);
  float var = sumsq[f] * (1.f / N_NODES) - mu * mu;
  float sc  = bn_w[f] * rsqrtf(var + BN_EPS);
  float sh_ = bn_b[f] - mu * sc;
  float w = W[f * 64 + oc];
  WpT[(size_t)o * NF + f] = __float2half(w * sc);
  red[f] = sh_ * w;
  __syncthreads();
  for (int off = 128; off > 0; off >>= 1){
    if (f < off) red[f] += red[f + off];
    __syncthreads();
  }
  if (f == 0) bp[o] = red[0];
}

// ---------------- attention projection vectors: wvec[12][256] + cbias[12] ----------------
// q = v*2+h (src), 6+v*2+h (dst). a_src[n] = x[n]·wvec[q] + cbias[q]  (BN folded)
__global__ __launch_bounds__(256) void k_avec(const float* __restrict__ sums, const float* __restrict__ sumsq,
                                              const float* __restrict__ bn_w, const float* __restrict__ bn_b,
                                              const float* __restrict__ WA, const float* __restrict__ asA, const float* __restrict__ adA,
                                              const float* __restrict__ WC, const float* __restrict__ asC, const float* __restrict__ adC,
                                              const float* __restrict__ WP, const float* __restrict__ asP, const float* __restrict__ adP,
                                              float* __restrict__ wvec, float* __restrict__ cbias){
  __shared__ float red[256];
  int f = threadIdx.x;
  float mu  = sums[f]  * (1.f / N_NODES);
  float var = sumsq[f] * (1.f / N_NODES) - mu * mu;
  float sc  = bn_w[f] * rsqrtf(var + BN_EPS);
  float sh_ = bn_b[f] - mu * sc;
  for (int v = 0; v < 3; ++v){
    const float* W  = (v == 0) ? WA : (v == 1) ? WC : WP;
    const float* As = (v == 0) ? asA : (v == 1) ? asC : asP;
    const float* Ad = (v == 0) ? adA : (v == 1) ? adC : adP;
    for (int h = 0; h < 2; ++h){
      float sa = 0.f, da = 0.f;
      for (int c = 0; c < 32; ++c){
        float w = W[f * 64 + h * 32 + c];
        sa += w * As[h * 32 + c];
        da += w * Ad[h * 32 + c];
      }
      int q = v * 2 + h;
      wvec[q * NF + f]       = sc * sa;
      wvec[(6 + q) * NF + f] = sc * da;
      // cbias reductions
      red[f] = sh_ * sa; __syncthreads();
      for (int off = 128; off > 0; off >>= 1){ if (f < off) red[f] += red[f + off]; __syncthreads(); }
      if (f == 0) cbias[q] = red[0];
      __syncthreads();
      red[f] = sh_ * da; __syncthreads();
      for (int off = 128; off > 0; off >>= 1){ if (f < off) red[f] += red[f + off]; __syncthreads(); }
      if (f == 0) cbias[6 + q] = red[0];
      __syncthreads();
    }
  }
}

// ---------------- attention logits directly from x (fp32 exact) + partial src-max ----------------
__global__ __launch_bounds__(256) void k_att2(const float* __restrict__ x,
                                              const float* __restrict__ wvec, const float* __restrict__ cbias,
                                              float* __restrict__ a_src, float* __restrict__ a_dst,
                                              unsigned* __restrict__ gpart){
  __shared__ float wv[12][256];
  __shared__ float cb[12];
  __shared__ unsigned samax[6];
  int t = threadIdx.x;
#pragma unroll
  for (int q = 0; q < 12; ++q) wv[q][t] = wvec[q * NF + t];
  if (t < 12) cb[t] = cbias[t];
  if (t < 6) samax[t] = 0u;
  __syncthreads();
  int grp = t >> 4, lid = t & 15;
  int n = blockIdx.x * 16 + grp;       // grid exact: 6250*16 = N_NODES
  float4 xr[4];
#pragma unroll
  for (int k = 0; k < 4; ++k)
    xr[k] = *(const float4*)(x + (size_t)n * NF + k * 64 + lid * 4);
  float res[12];
#pragma unroll
  for (int q = 0; q < 12; ++q){
    float acc = 0.f;
#pragma unroll
    for (int k = 0; k < 4; ++k){
      float4 wq = *(const float4*)&wv[q][k * 64 + lid * 4];
      acc += xr[k].x * wq.x + xr[k].y * wq.y + xr[k].z * wq.z + xr[k].w * wq.w;
    }
    acc += __shfl_xor(acc, 1, 16);
    acc += __shfl_xor(acc, 2, 16);
    acc += __shfl_xor(acc, 4, 16);
    acc += __shfl_xor(acc, 8, 16);
    res[q] = acc + cb[q];
  }
  if (lid == 0){
#pragma unroll
    for (int v = 0; v < 3; ++v){
      int g = v * N_NODES + n;
      *(float2*)(a_src + (size_t)g * 2) = make_float2(res[v*2+0], res[v*2+1]);
      *(float2*)(a_dst + (size_t)g * 2) = make_float2(res[6+v*2+0], res[6+v*2+1]);
      atomicMax(&samax[v*2+0], fenc(res[v*2+0]));
      atomicMax(&samax[v*2+1], fenc(res[v*2+1]));
    }
  }
  __syncthreads();
  if (t < 6) gpart[blockIdx.x * 6 + t] = samax[t];
}

// ---------------- reduce 6250x6 partials -> amax[6] ----------------
__global__ __launch_bounds__(256) void k_amax(const unsigned* __restrict__ gpart, unsigned* __restrict__ amax){
  __shared__ unsigned sm[6];
  int t = threadIdx.x;
  if (t < 6) sm[t] = 0u;
  __syncthreads();
  unsigned m[6] = {0u, 0u, 0u, 0u, 0u, 0u};
  for (int bi = t; bi < ATT2_NB; bi += 256){
    const unsigned* p = gpart + (size_t)bi * 6;
#pragma unroll
    for (int k = 0; k < 6; ++k) m[k] = max(m[k], p[k]);
  }
#pragma unroll
  for (int k = 0; k < 6; ++k) atomicMax(&sm[k], m[k]);
  __syncthreads();
  if (t < 6) amax[t] = sm[t];
}

// ---------------- exclusive scan (grain 8, 3 phases) ----------------
__global__ __launch_bounds__(256) void k_scan1(const int* __restrict__ cnt, int* __restrict__ out,
                                               int* __restrict__ bsum, int n){
  __shared__ int sh[256];
  int t = threadIdx.x; int base = blockIdx.x * 2048 + t * 8;
  int v[8]; int s = 0;
#pragma unroll
  for (int i = 0; i < 8; ++i){ v[i] = (base + i < n) ? cnt[base + i] : 0; s += v[i]; }
  sh[t] = s; __syncthreads();
  for (int off = 1; off < 256; off <<= 1){
    int xv = (t >= off) ? sh[t - off] : 0;
    __syncthreads();
    sh[t] += xv;
    __syncthreads();
  }
  int p = sh[t] - s;
  if (t == 255) bsum[blockIdx.x] = sh[255];
#pragma unroll
  for (int i = 0; i < 8; ++i){ if (base + i < n) out[base + i] = p; p += v[i]; }
}

__global__ __launch_bounds__(512) void k_scan2(int* __restrict__ bsum, int* __restrict__ total_out, int nb){
  __shared__ int sh[512];
  int t = threadIdx.x;
  int o = (t < nb) ? bsum[t] : 0;
  sh[t] = o; __syncthreads();
  for (int off = 1; off < 512; off <<= 1){
    int xv = (t >= off) ? sh[t - off] : 0;
    __syncthreads();
    sh[t] += xv;
    __syncthreads();
  }
  if (t < nb) bsum[t] = sh[t] - o;
  if (t == nb - 1) total_out[0] = sh[t];
}

__global__ __launch_bounds__(256) void k_scan3(int* __restrict__ out, const int* __restrict__ bsum, int n){
  int add = bsum[blockIdx.x];
  int base = blockIdx.x * 2048 + threadIdx.x * 8;
#pragma unroll
  for (int i = 0; i < 8; ++i) if (base + i < n) out[base + i] += add;
}

// ---------------- fused: MFMA fp16 GEMM + level-1 scatter WITH inline p-compute ----------------
#define GBM 64
#define GEMM_NB ((N_NODES + GBM - 1) / GBM)   // 1563
__global__ __launch_bounds__(256) void k_fused(const float* __restrict__ x,
                                               const __half* __restrict__ WpT, const float* __restrict__ bp,
                                               __half* __restrict__ h16,
                                               const int* __restrict__ eA, const int* __restrict__ eC,
                                               const int* __restrict__ eP,
                                               const float* __restrict__ a_src, const float* __restrict__ a_dst,
                                               const unsigned* __restrict__ amax,
                                               const int* __restrict__ gscan, uint2* __restrict__ ep){
  union U { _Float16 xs[64 * 256]; int pos[NBUCK]; };
  __shared__ U sm;
  __shared__ float sam_s[6];
  int t = threadIdx.x;
  if (blockIdx.x >= GEMM_NB){
    // -------- scatter path: LDS cursors + inline softmax numerator --------
    int bi = blockIdx.x - GEMM_NB;
    if (t < 6) sam_s[t] = fdec(amax[t]);
    for (int b = t; b < NBUCK; b += 256) sm.pos[b] = gscan[b * NB1 + bi];
    __syncthreads();
    int base = bi * ECHUNK + t;
#pragma unroll
    for (int k = 0; k < EGRAIN; ++k){
      int i = base + k * 256;
      if (i < NE3){
        int v = i / ETOT; int j = i - v * ETOT;
        const int* ei = (v == 0) ? eA : (v == 1) ? eC : eP;
        int s, d;
        if (j < N_EDGES){ s = ei[j]; d = ei[N_EDGES + j]; } else { s = j - N_EDGES; d = s; }
        int vd = v * N_NODES + d;
        float2 ad = *(const float2*)(a_dst + (size_t)vd * 2);
        float2 as = *(const float2*)(a_src + (size_t)(v * N_NODES + s) * 2);
        float m0 = lrelu(sam_s[v * 2 + 0] + ad.x);
        float m1 = lrelu(sam_s[v * 2 + 1] + ad.y);
        float p0 = __expf(lrelu(as.x + ad.x) - m0);
        float p1 = __expf(lrelu(as.y + ad.y) - m1);
        unsigned pu = (unsigned)__half_as_ushort(__float2half(p0))
                    | ((unsigned)__half_as_ushort(__float2half(p1)) << 16);
        int p = atomicAdd(&sm.pos[vd >> 9], 1);
        ep[p] = make_uint2((unsigned)s | ((unsigned)(vd & 511) << 17), pu);
      }
    }
    return;
  }
  // -------- MFMA GEMM path: tile 64 x 192, K=256 --------
  int m0 = blockIdx.x * GBM;
#pragma unroll
  for (int k = 0; k < 8; ++k){
    int G = t + k * 256;            // granule id 0..2047 (16B each)
    int row = G >> 5, g = G & 31;
    int grow = m0 + row; if (grow >= N_NODES) grow = N_NODES - 1;
    const float4* src = (const float4*)(x + (size_t)grow * NF + ((g ^ (row & 7)) << 3));
    float4 lo = src[0], hi = src[1];
    f16x8 h;
    h[0]=(_Float16)lo.x; h[1]=(_Float16)lo.y; h[2]=(_Float16)lo.z; h[3]=(_Float16)lo.w;
    h[4]=(_Float16)hi.x; h[5]=(_Float16)hi.y; h[6]=(_Float16)hi.z; h[7]=(_Float16)hi.w;
    *(f16x8*)&sm.xs[(size_t)G << 3] = h;
  }
  __syncthreads();
  int lane = t & 63, w = t >> 6;
  int lr = lane & 15, lk = lane >> 4;
  int colb = w * 48;                  // wave's 48 output cols
  f32x4 acc[4][3];
#pragma unroll
  for (int mt = 0; mt < 4; ++mt)
#pragma unroll
    for (int ct = 0; ct < 3; ++ct) acc[mt][ct] = (f32x4){0.f, 0.f, 0.f, 0.f};
  float bpv[3];
#pragma unroll
  for (int ct = 0; ct < 3; ++ct) bpv[ct] = bp[colb + ct * 16 + lr];
#pragma unroll
  for (int kk = 0; kk < 8; ++kk){
    int khalf = kk * 32 + lk * 8;
    f16x8 av[4];
#pragma unroll
    for (int mt = 0; mt < 4; ++mt){
      int row = mt * 16 + lr;
      av[mt] = *(const f16x8*)&sm.xs[row * 256 + (khalf ^ ((row & 7) << 3))];
    }
    f16x8 bv[3];
#pragma unroll
    for (int ct = 0; ct < 3; ++ct){
      int col = colb + ct * 16 + lr;
      bv[ct] = *(const f16x8*)(const void*)(WpT + (size_t)col * NF + khalf);
    }
#pragma unroll
    for (int mt = 0; mt < 4; ++mt)
#pragma unroll
      for (int ct = 0; ct < 3; ++ct)
        acc[mt][ct] = __builtin_amdgcn_mfma_f32_16x16x32_f16(av[mt], bv[ct], acc[mt][ct], 0, 0, 0);
  }
  // epilogue: C layout col=lane&15, row=(lane>>4)*4+reg
#pragma unroll
  for (int mt = 0; mt < 4; ++mt){
#pragma unroll
    for (int r = 0; r < 4; ++r){
      int row = m0 + mt * 16 + lk * 4 + r;
      if (row < N_NODES){
#pragma unroll
        for (int ct = 0; ct < 3; ++ct)
          h16[(size_t)row * NOUT3 + colb + ct * 16 + lr] = __float2half(acc[mt][ct][r] + bpv[ct]);
      }
    }
  }
}

// ---------------- level-2: light permute (no exp, no random reads) ----------------
__global__ __launch_bounds__(512) void k_build(const int* __restrict__ gscan, const uint2* __restrict__ ep,
                                               uint2* __restrict__ ep2, int* __restrict__ offsets){
  __shared__ int hist2[512];
  __shared__ int sh[512];
  int b = blockIdx.x, t = threadIdx.x;
  int base = gscan[b * NB1];
  int end  = (b == NBUCK - 1) ? NE3 : gscan[(b + 1) * NB1];
  hist2[t] = 0;
  __syncthreads();
  for (int i = base + t; i < end; i += 512)
    atomicAdd(&hist2[(ep[i].x >> 17) & 511], 1);
  __syncthreads();
  int cnt = hist2[t];
  sh[t] = cnt; __syncthreads();
  for (int off = 1; off < 512; off <<= 1){
    int xv = (t >= off) ? sh[t - off] : 0;
    __syncthreads();
    sh[t] += xv;
    __syncthreads();
  }
  int excl = sh[t] - cnt;
  hist2[t] = excl;                              // running cursor
  int vd0 = (b << 9) + t;
  if (vd0 < N3) offsets[vd0] = base + excl;
  if (b == NBUCK - 1 && t == 0) offsets[N3] = NE3;
  __syncthreads();
  for (int i = base + t; i < end; i += 512){
    uint2 e = ep[i];
    int low = (e.x >> 17) & 511;
    int pos = atomicAdd(&hist2[low], 1);
    ep2[base + pos] = make_uint2(e.x & 0x1FFFFu, e.y);
  }
}

// ---------------- gather: 16-lane groups, precomputed p, 8-deep pipeline (R8-proven) ----------------
__global__ __launch_bounds__(256) void k_gather(const uint2* __restrict__ ep2, const int* __restrict__ offsets,
                                                const __half* __restrict__ h16,
                                                const float* __restrict__ bA, const float* __restrict__ bC,
                                                const float* __restrict__ bP,
                                                const int* __restrict__ batch, unsigned* __restrict__ pooled){
  __shared__ unsigned red[64];
  __shared__ int kmin, kmax;
  int t = threadIdx.x;
  if (t == 0){ kmin = 0x7FFFFFFF; kmax = -1; }
  if (t < 64) red[t] = 0u;
  __syncthreads();
  int grp = t >> 4;
  int lid = t & 15;
  int g = blockIdx.x * 16 + grp;        // grid exact: N3/16 blocks
  int v = g / N_NODES; int n = g - v * N_NODES;
  int beg = offsets[g], end = offsets[g+1];
  int len = end - beg;
  float ax = 0.f, ay = 0.f, az = 0.f, aw = 0.f;
  float den0 = 0.f, den1 = 0.f;
  const __half* hbase = h16 + v * 64 + lid * 4;   // lane's 8B column slice
  for (int c0 = 0; c0 < len; c0 += 16){
    int nc = len - c0; if (nc > 16) nc = 16;
    int s_ = 0; unsigned pu_ = 0u;
    if (lid < nc){
      uint2 e = ep2[beg + c0 + lid];
      s_ = (int)e.x; pu_ = e.y;
    }
    den0 += __half2float(__ushort_as_half((unsigned short)(pu_ & 0xFFFFu)));
    den1 += __half2float(__ushort_as_half((unsigned short)(pu_ >> 16)));
    for (int k = 0; k < nc; k += 8){
      uint2 r[8]; float pa[8];
#pragma unroll
      for (int j = 0; j < 8; ++j){
        int kk = k + j;
        int sk = __shfl(s_, kk, 16);
        unsigned pk_ = (unsigned)__shfl((int)pu_, kk, 16);
        r[j] = *(const uint2*)(hbase + (size_t)sk * NOUT3);
        unsigned sel = (lid < 8) ? (pk_ & 0xFFFFu) : (pk_ >> 16);
        pa[j] = __half2float(__ushort_as_half((unsigned short)sel));
      }
#pragma unroll
      for (int j = 0; j < 8; ++j){
        float2 fa2 = __half22float2(*(__half2*)&r[j].x);
        float2 fb2 = __half22float2(*(__half2*)&r[j].y);
        ax = fmaf(pa[j], fa2.x, ax); ay = fmaf(pa[j], fa2.y, ay);
        az = fmaf(pa[j], fb2.x, az); aw = fmaf(pa[j], fb2.y, aw);
      }
    }
  }
#pragma unroll
  for (int msk = 1; msk < 16; msk <<= 1){
    den0 += __shfl_xor(den0, msk);
    den1 += __shfl_xor(den1, msk);
  }
  float den = ((lid < 8) ? den0 : den1) + 1e-16f;
  const float* bias = (v == 0) ? bA : (v == 1) ? bC : bP;
  float4 b4 = *(const float4*)(bias + lid * 4);
  unsigned e0u = fenc(eluf(ax / den + b4.x));
  unsigned e1u = fenc(eluf(ay / den + b4.y));
  unsigned e2u = fenc(eluf(az / den + b4.z));
  unsigned e3u = fenc(eluf(aw / den + b4.w));
  int key = v * NG + batch[n];
  if (lid == 0){ atomicMin(&kmin, key); atomicMax(&kmax, key); }
  atomicMax(&red[lid*4+0], e0u); atomicMax(&red[lid*4+1], e1u);
  atomicMax(&red[lid*4+2], e2u); atomicMax(&red[lid*4+3], e3u);
  __syncthreads();
  if (kmin == kmax){
    if (t < 64) atomicMax(&pooled[(size_t)kmin * 64 + t], red[t]);
  } else {
    unsigned* pp = pooled + (size_t)key * 64 + lid * 4;
    atomicMax(pp+0, e0u); atomicMax(pp+1, e1u); atomicMax(pp+2, e2u); atomicMax(pp+3, e3u);
  }
}

// ---------------- head MLP: one wave per graph ----------------
__global__ __launch_bounds__(64) void k_head(const unsigned* __restrict__ pooled,
                                             const float* __restrict__ g1w, const float* __restrict__ g1b,
                                             const float* __restrict__ g2w, const float* __restrict__ g2b,
                                             const float* __restrict__ c1w, const float* __restrict__ c1b,
                                             const float* __restrict__ c2w, const float* __restrict__ c2b,
                                             const float* __restrict__ c3w, const float* __restrict__ c3b,
                                             float* __restrict__ out){
  __shared__ float s1[64];
  __shared__ float s2[128];
  __shared__ float sw[3];
  int g = blockIdx.x, l = threadIdx.x;
  float ha = fdec(pooled[(size_t)g * 64 + l]);
  float hc = fdec(pooled[(size_t)(NG + g) * 64 + l]);
  float hp = fdec(pooled[(size_t)(2 * NG + g) * 64 + l]);
  s1[l] = (ha + hc + hp) * (1.f / 3.f);
  __syncthreads();
  float r1 = 0.f;
  if (l < 32){
    r1 = g1b[l];
    for (int i = 0; i < 64; ++i) r1 += s1[i] * g1w[i * 32 + l];
    r1 = fmaxf(r1, 0.f);
  }
  __syncthreads();
  if (l < 32) s2[l] = r1;
  __syncthreads();
  if (l < 3){
    float tv = g2b[l];
    for (int i = 0; i < 32; ++i) tv += s2[i] * g2w[i * 3 + l];
    sw[l] = tv;
  }
  __syncthreads();
  float t0 = sw[0], t1 = sw[1], t2 = sw[2];
  float mx = fmaxf(t0, fmaxf(t1, t2));
  float w0 = __expf(t0 - mx), w1 = __expf(t1 - mx), w2 = __expf(t2 - mx);
  float wsum = w0 + w1 + w2;
  float fused = (w0 * ha + w1 * hc + w2 * hp) / wsum;
  __syncthreads();
  s1[l] = fused;
  __syncthreads();
  float za = c1b[l], zb = c1b[64 + l];
  for (int i = 0; i < 64; ++i){
    float f = s1[i];
    za += f * c1w[i * 128 + l];
    zb += f * c1w[i * 128 + 64 + l];
  }
  za = fmaxf(za, 0.f); zb = fmaxf(zb, 0.f);
  s2[l] = za; s2[64 + l] = zb;
  __syncthreads();
  float z2 = c2b[l];
  for (int i = 0; i < 128; ++i) z2 += s2[i] * c2w[i * 64 + l];
  z2 = fmaxf(z2, 0.f);
  float prod = z2 * c3w[l];
  for (int off = 32; off > 0; off >>= 1) prod += __shfl_down(prod, off);
  if (l == 0) out[g] = prod + c3b[0];
}

extern "C" void kernel_launch(void* const* d_in, const int* in_sizes, int n_in,
                              void* d_out, int out_size, void* d_ws, size_t ws_size,
                              hipStream_t stream){
  const float* x    = (const float*)d_in[0];
  const int* eA     = (const int*)d_in[1];
  const int* eC     = (const int*)d_in[2];
  const int* eP     = (const int*)d_in[3];
  const int* batch  = (const int*)d_in[4];
  const float* bn_w = (const float*)d_in[6];
  const float* bn_b = (const float*)d_in[7];
  const float* WA   = (const float*)d_in[8];
  const float* asA  = (const float*)d_in[9];
  const float* adA  = (const float*)d_in[10];
  const float* bA   = (const float*)d_in[11];
  const float* WC   = (const float*)d_in[12];
  const float* asC  = (const float*)d_in[13];
  const float* adC  = (const float*)d_in[14];
  const float* bC   = (const float*)d_in[15];
  const float* WP   = (const float*)d_in[16];
  const float* asP  = (const float*)d_in[17];
  const float* adP  = (const float*)d_in[18];
  const float* bP   = (const float*)d_in[19];
  const float* g1w  = (const float*)d_in[20];
  const float* g1b  = (const float*)d_in[21];
  const float* g2w  = (const float*)d_in[22];
  const float* g2b  = (const float*)d_in[23];
  const float* c1w  = (const float*)d_in[24];
  const float* c1b  = (const float*)d_in[25];
  const float* c2w  = (const float*)d_in[26];
  const float* c2b  = (const float*)d_in[27];
  const float* c3w  = (const float*)d_in[28];
  const float* c3b  = (const float*)d_in[29];
  float* out = (float*)d_out;

  char* wptr = (char*)d_ws;
  auto alloc = [&](size_t bytes) -> void* {
    void* p = (void*)wptr;
    wptr += (bytes + 255) & ~(size_t)255;
    return p;
  };
  float*    sums    = (float*)   alloc((size_t)NF * 4);
  float*    sumsq   = (float*)   alloc((size_t)NF * 4);
  size_t zbytes = (size_t)(wptr - (char*)sums);
  int*      gcounts = (int*)     alloc((size_t)SCAN_N * 4);
  int*      gscan   = (int*)     alloc((size_t)SCAN_N * 4);
  int*      offsets = (int*)     alloc(((size_t)N3 + 1) * 4);
  __half*   WpT     = (__half*)  alloc((size_t)NOUT3 * NF * 2);
  float*    bp      = (float*)   alloc((size_t)NOUT3 * 4);
  float*    wvec    = (float*)   alloc((size_t)12 * NF * 4);
  float*    cbias   = (float*)   alloc((size_t)64 * 4);
  __half*   h16     = (__half*)  alloc((size_t)N_NODES * NOUT3 * 2);
  float*    a_src   = (float*)   alloc((size_t)N3 * 2 * 4);
  float*    a_dst   = (float*)   alloc((size_t)N3 * 2 * 4);
  uint2*    ep      = (uint2*)   alloc((size_t)NE3 * 8);
  uint2*    ep2     = (uint2*)   alloc((size_t)NE3 * 8);
  unsigned* pooled  = (unsigned*)alloc((size_t)3 * NG * NHC * 4);
  unsigned* gpart   = (unsigned*)alloc((size_t)ATT2_NB * 6 * 4);
  unsigned* amax    = (unsigned*)alloc((size_t)64 * 4);
  int*      bsum    = (int*)     alloc((size_t)512 * 4);
  int*      scrtot  = (int*)     alloc((size_t)64 * 4);

  hipMemsetAsync(sums, 0, zbytes, stream);
  k_init_pooled<<<(3 * NG * NHC + 255) / 256, 256, 0, stream>>>(pooled);
  k_pre<<<STATS_NB + NB1, 256, 0, stream>>>(x, sums, sumsq, eA, eC, eP, gcounts);
  k_prep2<<<NOUT3, 256, 0, stream>>>(sums, sumsq, bn_w, bn_b, WA, WC, WP, WpT, bp);
  k_avec<<<1, 256, 0, stream>>>(sums, sumsq, bn_w, bn_b, WA, asA, adA, WC, asC, adC, WP, asP, adP, wvec, cbias);
  int nb_sc = (SCAN_N + 2047) / 2048;   // 293
  k_scan1<<<nb_sc, 256, 0, stream>>>(gcounts, gscan, bsum, SCAN_N);
  k_scan2<<<1, 512, 0, stream>>>(bsum, scrtot, nb_sc);
  k_scan3<<<nb_sc, 256, 0, stream>>>(gscan, bsum, SCAN_N);
  k_att2<<<ATT2_NB, 256, 0, stream>>>(x, wvec, cbias, a_src, a_dst, gpart);
  k_amax<<<1, 256, 0, stream>>>(gpart, amax);
  k_fused<<<GEMM_NB + NB1, 256, 0, stream>>>(x, WpT, bp, h16, eA, eC, eP, a_src, a_dst, amax, gscan, ep);
  k_build<<<NBUCK, 512, 0, stream>>>(gscan, ep, ep2, offsets);
  k_gather<<<N3 / 16, 256, 0, stream>>>(ep2, offsets, h16, bA, bC, bP, batch, pooled);
  k_head<<<NG, 64, 0, stream>>>(pooled, g1w, g1b, g2w, g2b, c1w, c1b, c2w, c2b, c3w, c3b, out);
}

// Round 10
// 389.035 us; speedup vs baseline: 1.3130x; 1.3130x over previous
//
#include <hip/hip_runtime.h>
#include <hip/hip_bf16.h>
#include <hip/hip_fp16.h>

#define N_NODES 100000
#define N_EDGES 1600000
#define ETOT    (N_EDGES + N_NODES)   // 1,700,000
#define NE3     (3 * ETOT)            // 5,100,000
#define N3      (3 * N_NODES)         // 300,000
#define NF      256
#define NG      512
#define NHC     64
#define NOUT3   192
#define BN_EPS  1e-5f

// bucket sort params: 512-node buckets
#define NBUCK   586                   // ceil(300000/512)
#define NB1     1024                  // level-1 blocks
#define EGRAIN  20
#define ECHUNK  (256 * EGRAIN)        // 5120
#define SCAN_N  (NBUCK * NB1)         // 600064
#define ATT2_NB (N_NODES * 16 / 256)  // 6250

typedef _Float16 f16x8 __attribute__((ext_vector_type(8)));
typedef float    f32x4 __attribute__((ext_vector_type(4)));

__device__ __forceinline__ unsigned fenc(float f){
  unsigned b = __float_as_uint(f);
  return (b & 0x80000000u) ? ~b : (b | 0x80000000u);
}
__device__ __forceinline__ float fdec(unsigned u){
  unsigned b = (u & 0x80000000u) ? (u & 0x7FFFFFFFu) : ~u;
  return __uint_as_float(b);
}
__device__ __forceinline__ float lrelu(float x){ return x > 0.f ? x : 0.2f * x; }
__device__ __forceinline__ float eluf(float x){ return x > 0.f ? x : (__expf(x) - 1.f); }

// ---------------- init pooled to encoded -inf ----------------
__global__ void k_init_pooled(unsigned* pooled){
  int i = blockIdx.x * 256 + threadIdx.x;
  if (i < 3 * NG * NHC) pooled[i] = 0x007FFFFFu;   // fenc(-inf)
}

// ---------------- fused: column stats of x + level-1 edge histogram ----------------
#define STATS_NB ((N_NODES + 127) / 128)    // 782
__global__ __launch_bounds__(256) void k_pre(const float* __restrict__ x,
                                             float* __restrict__ sums, float* __restrict__ sumsq,
                                             const int* __restrict__ eA, const int* __restrict__ eC,
                                             const int* __restrict__ eP,
                                             int* __restrict__ gcounts){
  int t = threadIdx.x;
  if (blockIdx.x < STATS_NB){
    int r0 = blockIdx.x * 128;
    int rmax = N_NODES - r0; if (rmax > 128) rmax = 128;
    float s = 0.f, q = 0.f;
    for (int r = 0; r < rmax; ++r){
      float v = x[(size_t)(r0 + r) * NF + t];
      s += v; q += v * v;
    }
    atomicAdd(&sums[t], s);
    atomicAdd(&sumsq[t], q);
    return;
  }
  __shared__ int hist[NBUCK];
  int bi = blockIdx.x - STATS_NB;
  for (int b = t; b < NBUCK; b += 256) hist[b] = 0;
  __syncthreads();
  int base = bi * ECHUNK + t;
#pragma unroll
  for (int k = 0; k < EGRAIN; ++k){
    int i = base + k * 256;
    if (i < NE3){
      int v = i / ETOT; int j = i - v * ETOT;
      const int* ei = (v == 0) ? eA : (v == 1) ? eC : eP;
      int d = (j < N_EDGES) ? ei[N_EDGES + j] : (j - N_EDGES);
      int vd = v * N_NODES + d;
      atomicAdd(&hist[vd >> 9], 1);
    }
  }
  __syncthreads();
  for (int b = t; b < NBUCK; b += 256) gcounts[b * NB1 + bi] = hist[b];
}

// ---------------- fold BN into W'^T (fp16, [192][256]) and bias b' ----------------
__global__ __launch_bounds__(256) void k_prep2(const float* __restrict__ sums, const float* __restrict__ sumsq,
                                               const float* __restrict__ bn_w, const float* __restrict__ bn_b,
                                               const float* __restrict__ WA, const float* __restrict__ WC,
                                               const float* __restrict__ WP,
                                               __half* __restrict__ WpT, float* __restrict__ bp){
  __shared__ float red[256];
  int o = blockIdx.x;                 // 0..191
  int v = o >> 6, oc = o & 63;
  const float* W = (v == 0) ? WA : (v == 1) ? WC : WP;
  int f = threadIdx.x;
  float mu  = sums[f]  * (1.f / N_NODES);
  float var = sumsq[f] * (1.f / N_NODES) - mu * mu;
  float sc  = bn_w[f] * rsqrtf(var + BN_EPS);
  float sh_ = bn_b[f] - mu * sc;
  float w = W[f * 64 + oc];
  WpT[(size_t)o * NF + f] = __float2half(w * sc);
  red[f] = sh_ * w;
  __syncthreads();
  for (int off = 128; off > 0; off >>= 1){
    if (f < off) red[f] += red[f + off];
    __syncthreads();
  }
  if (f == 0) bp[o] = red[0];
}

// ---------------- attention projection vectors: wvec[12][256] + cbias[12] ----------------
__global__ __launch_bounds__(256) void k_avec(const float* __restrict__ sums, const float* __restrict__ sumsq,
                                              const float* __restrict__ bn_w, const float* __restrict__ bn_b,
                                              const float* __restrict__ WA, const float* __restrict__ asA, const float* __restrict__ adA,
                                              const float* __restrict__ WC, const float* __restrict__ asC, const float* __restrict__ adC,
                                              const float* __restrict__ WP, const float* __restrict__ asP, const float* __restrict__ adP,
                                              float* __restrict__ wvec, float* __restrict__ cbias){
  __shared__ float red[256];
  int f = threadIdx.x;
  float mu  = sums[f]  * (1.f / N_NODES);
  float var = sumsq[f] * (1.f / N_NODES) - mu * mu;
  float sc  = bn_w[f] * rsqrtf(var + BN_EPS);
  float sh_ = bn_b[f] - mu * sc;
  for (int v = 0; v < 3; ++v){
    const float* W  = (v == 0) ? WA : (v == 1) ? WC : WP;
    const float* As = (v == 0) ? asA : (v == 1) ? asC : asP;
    const float* Ad = (v == 0) ? adA : (v == 1) ? adC : adP;
    for (int h = 0; h < 2; ++h){
      float sa = 0.f, da = 0.f;
      for (int c = 0; c < 32; ++c){
        float w = W[f * 64 + h * 32 + c];
        sa += w * As[h * 32 + c];
        da += w * Ad[h * 32 + c];
      }
      int q = v * 2 + h;
      wvec[q * NF + f]       = sc * sa;
      wvec[(6 + q) * NF + f] = sc * da;
      red[f] = sh_ * sa; __syncthreads();
      for (int off = 128; off > 0; off >>= 1){ if (f < off) red[f] += red[f + off]; __syncthreads(); }
      if (f == 0) cbias[q] = red[0];
      __syncthreads();
      red[f] = sh_ * da; __syncthreads();
      for (int off = 128; off > 0; off >>= 1){ if (f < off) red[f] += red[f + off]; __syncthreads(); }
      if (f == 0) cbias[6 + q] = red[0];
      __syncthreads();
    }
  }
}

// ---------------- attention logits directly from x (fp32 exact) + partial src-max ----------------
__global__ __launch_bounds__(256) void k_att2(const float* __restrict__ x,
                                              const float* __restrict__ wvec, const float* __restrict__ cbias,
                                              float* __restrict__ a_src, float* __restrict__ a_dst,
                                              unsigned* __restrict__ gpart){
  __shared__ float wv[12][256];
  __shared__ float cb[12];
  __shared__ unsigned samax[6];
  int t = threadIdx.x;
#pragma unroll
  for (int q = 0; q < 12; ++q) wv[q][t] = wvec[q * NF + t];
  if (t < 12) cb[t] = cbias[t];
  if (t < 6) samax[t] = 0u;
  __syncthreads();
  int grp = t >> 4, lid = t & 15;
  int n = blockIdx.x * 16 + grp;       // grid exact: 6250*16 = N_NODES
  float4 xr[4];
#pragma unroll
  for (int k = 0; k < 4; ++k)
    xr[k] = *(const float4*)(x + (size_t)n * NF + k * 64 + lid * 4);
  float res[12];
#pragma unroll
  for (int q = 0; q < 12; ++q){
    float acc = 0.f;
#pragma unroll
    for (int k = 0; k < 4; ++k){
      float4 wq = *(const float4*)&wv[q][k * 64 + lid * 4];
      acc += xr[k].x * wq.x + xr[k].y * wq.y + xr[k].z * wq.z + xr[k].w * wq.w;
    }
    acc += __shfl_xor(acc, 1, 16);
    acc += __shfl_xor(acc, 2, 16);
    acc += __shfl_xor(acc, 4, 16);
    acc += __shfl_xor(acc, 8, 16);
    res[q] = acc + cb[q];
  }
  if (lid == 0){
#pragma unroll
    for (int v = 0; v < 3; ++v){
      int g = v * N_NODES + n;
      *(float2*)(a_src + (size_t)g * 2) = make_float2(res[v*2+0], res[v*2+1]);
      *(float2*)(a_dst + (size_t)g * 2) = make_float2(res[6+v*2+0], res[6+v*2+1]);
      atomicMax(&samax[v*2+0], fenc(res[v*2+0]));
      atomicMax(&samax[v*2+1], fenc(res[v*2+1]));
    }
  }
  __syncthreads();
  if (t < 6) gpart[blockIdx.x * 6 + t] = samax[t];
}

// ---------------- reduce 6250x6 partials -> amax[6] ----------------
__global__ __launch_bounds__(256) void k_amax(const unsigned* __restrict__ gpart, unsigned* __restrict__ amax){
  __shared__ unsigned sm[6];
  int t = threadIdx.x;
  if (t < 6) sm[t] = 0u;
  __syncthreads();
  unsigned m[6] = {0u, 0u, 0u, 0u, 0u, 0u};
  for (int bi = t; bi < ATT2_NB; bi += 256){
    const unsigned* p = gpart + (size_t)bi * 6;
#pragma unroll
    for (int k = 0; k < 6; ++k) m[k] = max(m[k], p[k]);
  }
#pragma unroll
  for (int k = 0; k < 6; ++k) atomicMax(&sm[k], m[k]);
  __syncthreads();
  if (t < 6) amax[t] = sm[t];
}

// ---------------- exclusive scan (grain 8, 3 phases) ----------------
__global__ __launch_bounds__(256) void k_scan1(const int* __restrict__ cnt, int* __restrict__ out,
                                               int* __restrict__ bsum, int n){
  __shared__ int sh[256];
  int t = threadIdx.x; int base = blockIdx.x * 2048 + t * 8;
  int v[8]; int s = 0;
#pragma unroll
  for (int i = 0; i < 8; ++i){ v[i] = (base + i < n) ? cnt[base + i] : 0; s += v[i]; }
  sh[t] = s; __syncthreads();
  for (int off = 1; off < 256; off <<= 1){
    int xv = (t >= off) ? sh[t - off] : 0;
    __syncthreads();
    sh[t] += xv;
    __syncthreads();
  }
  int p = sh[t] - s;
  if (t == 255) bsum[blockIdx.x] = sh[255];
#pragma unroll
  for (int i = 0; i < 8; ++i){ if (base + i < n) out[base + i] = p; p += v[i]; }
}

__global__ __launch_bounds__(512) void k_scan2(int* __restrict__ bsum, int* __restrict__ total_out, int nb){
  __shared__ int sh[512];
  int t = threadIdx.x;
  int o = (t < nb) ? bsum[t] : 0;
  sh[t] = o; __syncthreads();
  for (int off = 1; off < 512; off <<= 1){
    int xv = (t >= off) ? sh[t - off] : 0;
    __syncthreads();
    sh[t] += xv;
    __syncthreads();
  }
  if (t < nb) bsum[t] = sh[t] - o;
  if (t == nb - 1) total_out[0] = sh[t];
}

__global__ __launch_bounds__(256) void k_scan3(int* __restrict__ out, const int* __restrict__ bsum, int n){
  int add = bsum[blockIdx.x];
  int base = blockIdx.x * 2048 + threadIdx.x * 8;
#pragma unroll
  for (int i = 0; i < 8; ++i) if (base + i < n) out[base + i] += add;
}

// ---------------- fused: MFMA fp16 GEMM + light level-1 scatter (index-only) ----------------
#define GBM 64
#define GEMM_NB ((N_NODES + GBM - 1) / GBM)   // 1563
__global__ __launch_bounds__(256) void k_fused(const float* __restrict__ x,
                                               const __half* __restrict__ WpT, const float* __restrict__ bp,
                                               __half* __restrict__ h16,
                                               const int* __restrict__ eA, const int* __restrict__ eC,
                                               const int* __restrict__ eP,
                                               const int* __restrict__ gscan, int* __restrict__ packed){
  union U { _Float16 xs[64 * 256]; int pos[NBUCK]; };
  __shared__ U sm;
  int t = threadIdx.x;
  if (blockIdx.x >= GEMM_NB){
    int bi = blockIdx.x - GEMM_NB;
    for (int b = t; b < NBUCK; b += 256) sm.pos[b] = gscan[b * NB1 + bi];
    __syncthreads();
    int base = bi * ECHUNK + t;
#pragma unroll
    for (int k = 0; k < EGRAIN; ++k){
      int i = base + k * 256;
      if (i < NE3){
        int v = i / ETOT; int j = i - v * ETOT;
        const int* ei = (v == 0) ? eA : (v == 1) ? eC : eP;
        int s, d;
        if (j < N_EDGES){ s = ei[j]; d = ei[N_EDGES + j]; } else { s = j - N_EDGES; d = s; }
        int vd = v * N_NODES + d;
        int p = atomicAdd(&sm.pos[vd >> 9], 1);
        packed[p] = s | ((vd & 511) << 17);
      }
    }
    return;
  }
  // -------- MFMA GEMM path: tile 64 x 192, K=256 --------
  int m0 = blockIdx.x * GBM;
#pragma unroll
  for (int k = 0; k < 8; ++k){
    int G = t + k * 256;            // granule id 0..2047 (16B each)
    int row = G >> 5, g = G & 31;
    int grow = m0 + row; if (grow >= N_NODES) grow = N_NODES - 1;
    const float4* src = (const float4*)(x + (size_t)grow * NF + ((g ^ (row & 7)) << 3));
    float4 lo = src[0], hi = src[1];
    f16x8 h;
    h[0]=(_Float16)lo.x; h[1]=(_Float16)lo.y; h[2]=(_Float16)lo.z; h[3]=(_Float16)lo.w;
    h[4]=(_Float16)hi.x; h[5]=(_Float16)hi.y; h[6]=(_Float16)hi.z; h[7]=(_Float16)hi.w;
    *(f16x8*)&sm.xs[(size_t)G << 3] = h;
  }
  __syncthreads();
  int lane = t & 63, w = t >> 6;
  int lr = lane & 15, lk = lane >> 4;
  int colb = w * 48;                  // wave's 48 output cols
  f32x4 acc[4][3];
#pragma unroll
  for (int mt = 0; mt < 4; ++mt)
#pragma unroll
    for (int ct = 0; ct < 3; ++ct) acc[mt][ct] = (f32x4){0.f, 0.f, 0.f, 0.f};
  float bpv[3];
#pragma unroll
  for (int ct = 0; ct < 3; ++ct) bpv[ct] = bp[colb + ct * 16 + lr];
#pragma unroll
  for (int kk = 0; kk < 8; ++kk){
    int khalf = kk * 32 + lk * 8;
    f16x8 av[4];
#pragma unroll
    for (int mt = 0; mt < 4; ++mt){
      int row = mt * 16 + lr;
      av[mt] = *(const f16x8*)&sm.xs[row * 256 + (khalf ^ ((row & 7) << 3))];
    }
    f16x8 bv[3];
#pragma unroll
    for (int ct = 0; ct < 3; ++ct){
      int col = colb + ct * 16 + lr;
      bv[ct] = *(const f16x8*)(const void*)(WpT + (size_t)col * NF + khalf);
    }
#pragma unroll
    for (int mt = 0; mt < 4; ++mt)
#pragma unroll
      for (int ct = 0; ct < 3; ++ct)
        acc[mt][ct] = __builtin_amdgcn_mfma_f32_16x16x32_f16(av[mt], bv[ct], acc[mt][ct], 0, 0, 0);
  }
#pragma unroll
  for (int mt = 0; mt < 4; ++mt){
#pragma unroll
    for (int r = 0; r < 4; ++r){
      int row = m0 + mt * 16 + lk * 4 + r;
      if (row < N_NODES){
#pragma unroll
        for (int ct = 0; ct < 3; ++ct)
          h16[(size_t)row * NOUT3 + colb + ct * 16 + lr] = __float2half(acc[mt][ct][r] + bpv[ct]);
      }
    }
  }
}

// ---------------- level-2: light permute (no exp, no random reads) ----------------
__global__ __launch_bounds__(512) void k_build(const int* __restrict__ gscan, const int* __restrict__ packed,
                                               int* __restrict__ entries, int* __restrict__ offsets){
  __shared__ int hist2[512];
  __shared__ int sh[512];
  int b = blockIdx.x, t = threadIdx.x;
  int base = gscan[b * NB1];
  int end  = (b == NBUCK - 1) ? NE3 : gscan[(b + 1) * NB1];
  hist2[t] = 0;
  __syncthreads();
  for (int i = base + t; i < end; i += 512)
    atomicAdd(&hist2[(packed[i] >> 17) & 511], 1);
  __syncthreads();
  int cnt = hist2[t];
  sh[t] = cnt; __syncthreads();
  for (int off = 1; off < 512; off <<= 1){
    int xv = (t >= off) ? sh[t - off] : 0;
    __syncthreads();
    sh[t] += xv;
    __syncthreads();
  }
  int excl = sh[t] - cnt;
  hist2[t] = excl;                              // running cursor
  int vd0 = (b << 9) + t;
  if (vd0 < N3) offsets[vd0] = base + excl;
  if (b == NBUCK - 1 && t == 0) offsets[N3] = NE3;
  __syncthreads();
  for (int i = base + t; i < end; i += 512){
    int pk = packed[i];
    int low = (pk >> 17) & 511;
    int pos = atomicAdd(&hist2[low], 1);
    entries[base + pos] = pk & 0x1FFFF;
  }
}

// ---------------- gather: 16-lane groups, inline exp (phase A) + 8-deep pipeline (phase B) ----------------
__global__ __launch_bounds__(256) void k_gather(const int* __restrict__ entries, const int* __restrict__ offsets,
                                                const float* __restrict__ a_src, const float* __restrict__ a_dst,
                                                const unsigned* __restrict__ amax,
                                                const __half* __restrict__ h16,
                                                const float* __restrict__ bA, const float* __restrict__ bC,
                                                const float* __restrict__ bP,
                                                const int* __restrict__ batch, unsigned* __restrict__ pooled){
  __shared__ unsigned red[64];
  __shared__ int kmin, kmax;
  int t = threadIdx.x;
  if (t == 0){ kmin = 0x7FFFFFFF; kmax = -1; }
  if (t < 64) red[t] = 0u;
  __syncthreads();
  int grp = t >> 4;
  int lid = t & 15;
  int g = blockIdx.x * 16 + grp;        // grid exact: N3/16 blocks
  int v = g / N_NODES; int n = g - v * N_NODES;
  int vN = v * N_NODES;
  float ad0 = a_dst[g*2+0], ad1 = a_dst[g*2+1];
  float m0 = lrelu(fdec(amax[v*2+0]) + ad0);   // >= max edge logit for this dst
  float m1 = lrelu(fdec(amax[v*2+1]) + ad1);
  int beg = offsets[g], end = offsets[g+1];
  int len = end - beg;
  float ax = 0.f, ay = 0.f, az = 0.f, aw = 0.f;
  float den0 = 0.f, den1 = 0.f;
  const __half* hbase = h16 + v * 64 + lid * 4;   // lane's 8B column slice
  for (int c0 = 0; c0 < len; c0 += 16){
    int nc = len - c0; if (nc > 16) nc = 16;
    // phase A: one edge per lane — coalesced entries read, exp pair, pack to fp16
    int s_ = 0; unsigned pu_ = 0u;
    if (lid < nc){
      s_ = entries[beg + c0 + lid];
      float2 ap = *(const float2*)(a_src + (size_t)(vN + s_) * 2);
      float p0 = __expf(lrelu(ap.x + ad0) - m0);
      float p1 = __expf(lrelu(ap.y + ad1) - m1);
      pu_ = (unsigned)__half_as_ushort(__float2half(p0))
          | ((unsigned)__half_as_ushort(__float2half(p1)) << 16);
    }
    den0 += __half2float(__ushort_as_half((unsigned short)(pu_ & 0xFFFFu)));
    den1 += __half2float(__ushort_as_half((unsigned short)(pu_ >> 16)));
    // phase B: broadcast + aggregate, 8-deep load pipeline (lanes kk>=nc carry p=0)
    for (int k = 0; k < nc; k += 8){
      uint2 r[8]; float pa[8];
#pragma unroll
      for (int j = 0; j < 8; ++j){
        int kk = k + j;
        int sk = __shfl(s_, kk, 16);
        unsigned pk_ = (unsigned)__shfl((int)pu_, kk, 16);
        r[j] = *(const uint2*)(hbase + (size_t)sk * NOUT3);
        unsigned sel = (lid < 8) ? (pk_ & 0xFFFFu) : (pk_ >> 16);
        pa[j] = __half2float(__ushort_as_half((unsigned short)sel));
      }
#pragma unroll
      for (int j = 0; j < 8; ++j){
        float2 fa2 = __half22float2(*(__half2*)&r[j].x);
        float2 fb2 = __half22float2(*(__half2*)&r[j].y);
        ax = fmaf(pa[j], fa2.x, ax); ay = fmaf(pa[j], fa2.y, ay);
        az = fmaf(pa[j], fb2.x, az); aw = fmaf(pa[j], fb2.y, aw);
      }
    }
  }
#pragma unroll
  for (int msk = 1; msk < 16; msk <<= 1){
    den0 += __shfl_xor(den0, msk);
    den1 += __shfl_xor(den1, msk);
  }
  float den = ((lid < 8) ? den0 : den1) + 1e-16f;
  const float* bias = (v == 0) ? bA : (v == 1) ? bC : bP;
  float4 b4 = *(const float4*)(bias + lid * 4);
  unsigned e0u = fenc(eluf(ax / den + b4.x));
  unsigned e1u = fenc(eluf(ay / den + b4.y));
  unsigned e2u = fenc(eluf(az / den + b4.z));
  unsigned e3u = fenc(eluf(aw / den + b4.w));
  int key = v * NG + batch[n];
  if (lid == 0){ atomicMin(&kmin, key); atomicMax(&kmax, key); }
  atomicMax(&red[lid*4+0], e0u); atomicMax(&red[lid*4+1], e1u);
  atomicMax(&red[lid*4+2], e2u); atomicMax(&red[lid*4+3], e3u);
  __syncthreads();
  if (kmin == kmax){
    if (t < 64) atomicMax(&pooled[(size_t)kmin * 64 + t], red[t]);
  } else {
    unsigned* pp = pooled + (size_t)key * 64 + lid * 4;
    atomicMax(pp+0, e0u); atomicMax(pp+1, e1u); atomicMax(pp+2, e2u); atomicMax(pp+3, e3u);
  }
}

// ---------------- head MLP: one wave per graph ----------------
__global__ __launch_bounds__(64) void k_head(const unsigned* __restrict__ pooled,
                                             const float* __restrict__ g1w, const float* __restrict__ g1b,
                                             const float* __restrict__ g2w, const float* __restrict__ g2b,
                                             const float* __restrict__ c1w, const float* __restrict__ c1b,
                                             const float* __restrict__ c2w, const float* __restrict__ c2b,
                                             const float* __restrict__ c3w, const float* __restrict__ c3b,
                                             float* __restrict__ out){
  __shared__ float s1[64];
  __shared__ float s2[128];
  __shared__ float sw[3];
  int g = blockIdx.x, l = threadIdx.x;
  float ha = fdec(pooled[(size_t)g * 64 + l]);
  float hc = fdec(pooled[(size_t)(NG + g) * 64 + l]);
  float hp = fdec(pooled[(size_t)(2 * NG + g) * 64 + l]);
  s1[l] = (ha + hc + hp) * (1.f / 3.f);
  __syncthreads();
  float r1 = 0.f;
  if (l < 32){
    r1 = g1b[l];
    for (int i = 0; i < 64; ++i) r1 += s1[i] * g1w[i * 32 + l];
    r1 = fmaxf(r1, 0.f);
  }
  __syncthreads();
  if (l < 32) s2[l] = r1;
  __syncthreads();
  if (l < 3){
    float tv = g2b[l];
    for (int i = 0; i < 32; ++i) tv += s2[i] * g2w[i * 3 + l];
    sw[l] = tv;
  }
  __syncthreads();
  float t0 = sw[0], t1 = sw[1], t2 = sw[2];
  float mx = fmaxf(t0, fmaxf(t1, t2));
  float w0 = __expf(t0 - mx), w1 = __expf(t1 - mx), w2 = __expf(t2 - mx);
  float wsum = w0 + w1 + w2;
  float fused = (w0 * ha + w1 * hc + w2 * hp) / wsum;
  __syncthreads();
  s1[l] = fused;
  __syncthreads();
  float za = c1b[l], zb = c1b[64 + l];
  for (int i = 0; i < 64; ++i){
    float f = s1[i];
    za += f * c1w[i * 128 + l];
    zb += f * c1w[i * 128 + 64 + l];
  }
  za = fmaxf(za, 0.f); zb = fmaxf(zb, 0.f);
  s2[l] = za; s2[64 + l] = zb;
  __syncthreads();
  float z2 = c2b[l];
  for (int i = 0; i < 128; ++i) z2 += s2[i] * c2w[i * 64 + l];
  z2 = fmaxf(z2, 0.f);
  float prod = z2 * c3w[l];
  for (int off = 32; off > 0; off >>= 1) prod += __shfl_down(prod, off);
  if (l == 0) out[g] = prod + c3b[0];
}

extern "C" void kernel_launch(void* const* d_in, const int* in_sizes, int n_in,
                              void* d_out, int out_size, void* d_ws, size_t ws_size,
                              hipStream_t stream){
  const float* x    = (const float*)d_in[0];
  const int* eA     = (const int*)d_in[1];
  const int* eC     = (const int*)d_in[2];
  const int* eP     = (const int*)d_in[3];
  const int* batch  = (const int*)d_in[4];
  const float* bn_w = (const float*)d_in[6];
  const float* bn_b = (const float*)d_in[7];
  const float* WA   = (const float*)d_in[8];
  const float* asA  = (const float*)d_in[9];
  const float* adA  = (const float*)d_in[10];
  const float* bA   = (const float*)d_in[11];
  const float* WC   = (const float*)d_in[12];
  const float* asC  = (const float*)d_in[13];
  const float* adC  = (const float*)d_in[14];
  const float* bC   = (const float*)d_in[15];
  const float* WP   = (const float*)d_in[16];
  const float* asP  = (const float*)d_in[17];
  const float* adP  = (const float*)d_in[18];
  const float* bP   = (const float*)d_in[19];
  const float* g1w  = (const float*)d_in[20];
  const float* g1b  = (const float*)d_in[21];
  const float* g2w  = (const float*)d_in[22];
  const float* g2b  = (const float*)d_in[23];
  const float* c1w  = (const float*)d_in[24];
  const float* c1b  = (const float*)d_in[25];
  const float* c2w  = (const float*)d_in[26];
  const float* c2b  = (const float*)d_in[27];
  const float* c3w  = (const float*)d_in[28];
  const float* c3b  = (const float*)d_in[29];
  float* out = (float*)d_out;

  char* wptr = (char*)d_ws;
  auto alloc = [&](size_t bytes) -> void* {
    void* p = (void*)wptr;
    wptr += (bytes + 255) & ~(size_t)255;
    return p;
  };
  float*    sums    = (float*)   alloc((size_t)NF * 4);
  float*    sumsq   = (float*)   alloc((size_t)NF * 4);
  size_t zbytes = (size_t)(wptr - (char*)sums);
  int*      gcounts = (int*)     alloc((size_t)SCAN_N * 4);
  int*      gscan   = (int*)     alloc((size_t)SCAN_N * 4);
  int*      offsets = (int*)     alloc(((size_t)N3 + 1) * 4);
  __half*   WpT     = (__half*)  alloc((size_t)NOUT3 * NF * 2);
  float*    bp      = (float*)   alloc((size_t)NOUT3 * 4);
  float*    wvec    = (float*)   alloc((size_t)12 * NF * 4);
  float*    cbias   = (float*)   alloc((size_t)64 * 4);
  __half*   h16     = (__half*)  alloc((size_t)N_NODES * NOUT3 * 2);
  float*    a_src   = (float*)   alloc((size_t)N3 * 2 * 4);
  float*    a_dst   = (float*)   alloc((size_t)N3 * 2 * 4);
  int*      packed  = (int*)     alloc((size_t)NE3 * 4);
  int*      entries = (int*)     alloc((size_t)NE3 * 4);
  unsigned* pooled  = (unsigned*)alloc((size_t)3 * NG * NHC * 4);
  unsigned* gpart   = (unsigned*)alloc((size_t)ATT2_NB * 6 * 4);
  unsigned* amax    = (unsigned*)alloc((size_t)64 * 4);
  int*      bsum    = (int*)     alloc((size_t)512 * 4);
  int*      scrtot  = (int*)     alloc((size_t)64 * 4);

  hipMemsetAsync(sums, 0, zbytes, stream);
  k_init_pooled<<<(3 * NG * NHC + 255) / 256, 256, 0, stream>>>(pooled);
  k_pre<<<STATS_NB + NB1, 256, 0, stream>>>(x, sums, sumsq, eA, eC, eP, gcounts);
  k_prep2<<<NOUT3, 256, 0, stream>>>(sums, sumsq, bn_w, bn_b, WA, WC, WP, WpT, bp);
  k_avec<<<1, 256, 0, stream>>>(sums, sumsq, bn_w, bn_b, WA, asA, adA, WC, asC, adC, WP, asP, adP, wvec, cbias);
  int nb_sc = (SCAN_N + 2047) / 2048;   // 293
  k_scan1<<<nb_sc, 256, 0, stream>>>(gcounts, gscan, bsum, SCAN_N);
  k_scan2<<<1, 512, 0, stream>>>(bsum, scrtot, nb_sc);
  k_scan3<<<nb_sc, 256, 0, stream>>>(gscan, bsum, SCAN_N);
  k_att2<<<ATT2_NB, 256, 0, stream>>>(x, wvec, cbias, a_src, a_dst, gpart);
  k_amax<<<1, 256, 0, stream>>>(gpart, amax);
  k_fused<<<GEMM_NB + NB1, 256, 0, stream>>>(x, WpT, bp, h16, eA, eC, eP, gscan, packed);
  k_build<<<NBUCK, 512, 0, stream>>>(gscan, packed, entries, offsets);
  k_gather<<<N3 / 16, 256, 0, stream>>>(entries, offsets, a_src, a_dst, amax, h16, bA, bC, bP, batch, pooled);
  k_head<<<NG, 64, 0, stream>>>(pooled, g1w, g1b, g2w, g2b, c1w, c1b, c2w, c2b, c3w, c3b, out);
}

// Round 12
// 380.067 us; speedup vs baseline: 1.3440x; 1.0236x over previous
//
#include <hip/hip_runtime.h>
#include <hip/hip_bf16.h>
#include <hip/hip_fp16.h>

#define N_NODES 100000
#define N_EDGES 1600000
#define ETOT    (N_EDGES + N_NODES)   // 1,700,000
#define NE3     (3 * ETOT)            // 5,100,000
#define N3      (3 * N_NODES)         // 300,000
#define NF      256
#define NG      512
#define NHC     64
#define NOUT3   192
#define BN_EPS  1e-5f

// bucket sort params: 512-node buckets
#define NBUCK   586                   // ceil(300000/512)
#define NB1     1024                  // level-1 blocks
#define EGRAIN  20
#define ECHUNK  (256 * EGRAIN)        // 5120
#define SCAN_N  (NBUCK * NB1)         // 600064
#define ATT2_NB (N_NODES * 16 / 256)  // 6250

typedef _Float16 f16x8 __attribute__((ext_vector_type(8)));
typedef float    f32x4 __attribute__((ext_vector_type(4)));

__device__ __forceinline__ unsigned fenc(float f){
  unsigned b = __float_as_uint(f);
  return (b & 0x80000000u) ? ~b : (b | 0x80000000u);
}
__device__ __forceinline__ float fdec(unsigned u){
  unsigned b = (u & 0x80000000u) ? (u & 0x7FFFFFFFu) : ~u;
  return __uint_as_float(b);
}
__device__ __forceinline__ float lrelu(float x){ return x > 0.f ? x : 0.2f * x; }
__device__ __forceinline__ float eluf(float x){ return x > 0.f ? x : (__expf(x) - 1.f); }

// ---------------- init pooled to encoded -inf ----------------
__global__ void k_init_pooled(unsigned* pooled){
  int i = blockIdx.x * 256 + threadIdx.x;
  if (i < 3 * NG * NHC) pooled[i] = 0x007FFFFFu;   // fenc(-inf)
}

// ---------------- fused: column-stat partials (deterministic) + level-1 edge histogram ----------------
#define STATS_NB ((N_NODES + 127) / 128)    // 782
__global__ __launch_bounds__(256) void k_pre(const float* __restrict__ x,
                                             float* __restrict__ spartS, float* __restrict__ spartQ,
                                             const int* __restrict__ eA, const int* __restrict__ eC,
                                             const int* __restrict__ eP,
                                             int* __restrict__ gcounts){
  int t = threadIdx.x;
  if (blockIdx.x < STATS_NB){
    int r0 = blockIdx.x * 128;
    int rmax = N_NODES - r0; if (rmax > 128) rmax = 128;
    float s = 0.f, q = 0.f;
    for (int r = 0; r < rmax; ++r){
      float v = x[(size_t)(r0 + r) * NF + t];
      s += v; q += v * v;
    }
    spartS[(size_t)t * STATS_NB + blockIdx.x] = s;   // plain stores, no atomics
    spartQ[(size_t)t * STATS_NB + blockIdx.x] = q;
    return;
  }
  __shared__ int hist[NBUCK];
  int bi = blockIdx.x - STATS_NB;
  for (int b = t; b < NBUCK; b += 256) hist[b] = 0;
  __syncthreads();
  int base = bi * ECHUNK + t;
#pragma unroll
  for (int k = 0; k < EGRAIN; ++k){
    int i = base + k * 256;
    if (i < NE3){
      int v = i / ETOT; int j = i - v * ETOT;
      const int* ei = (v == 0) ? eA : (v == 1) ? eC : eP;
      int d = (j < N_EDGES) ? ei[N_EDGES + j] : (j - N_EDGES);
      int vd = v * N_NODES + d;
      atomicAdd(&hist[vd >> 9], 1);
    }
  }
  __syncthreads();
  for (int b = t; b < NBUCK; b += 256) gcounts[b * NB1 + bi] = hist[b];
}

// ---------------- deterministic fixed-order reduction of column stats ----------------
__global__ __launch_bounds__(256) void k_stats2(const float* __restrict__ spartS, const float* __restrict__ spartQ,
                                                float* __restrict__ sums, float* __restrict__ sumsq){
  __shared__ float rs[256], rq[256];
  int c = blockIdx.x, i = threadIdx.x;
  float s = 0.f, q = 0.f;
  for (int b = i; b < STATS_NB; b += 256){
    s += spartS[(size_t)c * STATS_NB + b];
    q += spartQ[(size_t)c * STATS_NB + b];
  }
  rs[i] = s; rq[i] = q;
  __syncthreads();
  for (int off = 128; off > 0; off >>= 1){
    if (i < off){ rs[i] += rs[i + off]; rq[i] += rq[i + off]; }
    __syncthreads();
  }
  if (i == 0){ sums[c] = rs[0]; sumsq[c] = rq[0]; }
}

// ---------------- fold BN into W'^T (fp16) + bias; block NOUT3 computes wvec/cbias ----------------
__global__ __launch_bounds__(256) void k_prep2(const float* __restrict__ sums, const float* __restrict__ sumsq,
                                               const float* __restrict__ bn_w, const float* __restrict__ bn_b,
                                               const float* __restrict__ WA, const float* __restrict__ asA, const float* __restrict__ adA,
                                               const float* __restrict__ WC, const float* __restrict__ asC, const float* __restrict__ adC,
                                               const float* __restrict__ WP, const float* __restrict__ asP, const float* __restrict__ adP,
                                               __half* __restrict__ WpT, float* __restrict__ bp,
                                               float* __restrict__ wvec, float* __restrict__ cbias){
  __shared__ float red[256];
  int f = threadIdx.x;
  float mu  = sums[f]  * (1.f / N_NODES);
  float var = sumsq[f] * (1.f / N_NODES) - mu * mu;
  float sc  = bn_w[f] * rsqrtf(var + BN_EPS);
  float sh_ = bn_b[f] - mu * sc;
  int o = blockIdx.x;
  if (o < NOUT3){
    int v = o >> 6, oc = o & 63;
    const float* W = (v == 0) ? WA : (v == 1) ? WC : WP;
    float w = W[f * 64 + oc];
    WpT[(size_t)o * NF + f] = __float2half(w * sc);
    red[f] = sh_ * w;
    __syncthreads();
    for (int off = 128; off > 0; off >>= 1){
      if (f < off) red[f] += red[f + off];
      __syncthreads();
    }
    if (f == 0) bp[o] = red[0];
    return;
  }
  // avec path (block NOUT3)
  for (int v = 0; v < 3; ++v){
    const float* W  = (v == 0) ? WA : (v == 1) ? WC : WP;
    const float* As = (v == 0) ? asA : (v == 1) ? asC : asP;
    const float* Ad = (v == 0) ? adA : (v == 1) ? adC : adP;
    for (int h = 0; h < 2; ++h){
      float sa = 0.f, da = 0.f;
      for (int c = 0; c < 32; ++c){
        float w = W[f * 64 + h * 32 + c];
        sa += w * As[h * 32 + c];
        da += w * Ad[h * 32 + c];
      }
      int q = v * 2 + h;
      wvec[q * NF + f]       = sc * sa;
      wvec[(6 + q) * NF + f] = sc * da;
      red[f] = sh_ * sa; __syncthreads();
      for (int off = 128; off > 0; off >>= 1){ if (f < off) red[f] += red[f + off]; __syncthreads(); }
      if (f == 0) cbias[q] = red[0];
      __syncthreads();
      red[f] = sh_ * da; __syncthreads();
      for (int off = 128; off > 0; off >>= 1){ if (f < off) red[f] += red[f + off]; __syncthreads(); }
      if (f == 0) cbias[6 + q] = red[0];
      __syncthreads();
    }
  }
}

// ---------------- exclusive scan (grain 8, 3 phases) ----------------
__global__ __launch_bounds__(256) void k_scan1(const int* __restrict__ cnt, int* __restrict__ out,
                                               int* __restrict__ bsum, int n){
  __shared__ int sh[256];
  int t = threadIdx.x; int base = blockIdx.x * 2048 + t * 8;
  int v[8]; int s = 0;
#pragma unroll
  for (int i = 0; i < 8; ++i){ v[i] = (base + i < n) ? cnt[base + i] : 0; s += v[i]; }
  sh[t] = s; __syncthreads();
  for (int off = 1; off < 256; off <<= 1){
    int xv = (t >= off) ? sh[t - off] : 0;
    __syncthreads();
    sh[t] += xv;
    __syncthreads();
  }
  int p = sh[t] - s;
  if (t == 255) bsum[blockIdx.x] = sh[255];
#pragma unroll
  for (int i = 0; i < 8; ++i){ if (base + i < n) out[base + i] = p; p += v[i]; }
}

__global__ __launch_bounds__(512) void k_scan2(int* __restrict__ bsum, int* __restrict__ total_out, int nb){
  __shared__ int sh[512];
  int t = threadIdx.x;
  int o = (t < nb) ? bsum[t] : 0;
  sh[t] = o; __syncthreads();
  for (int off = 1; off < 512; off <<= 1){
    int xv = (t >= off) ? sh[t - off] : 0;
    __syncthreads();
    sh[t] += xv;
    __syncthreads();
  }
  if (t < nb) bsum[t] = sh[t] - o;
  if (t == nb - 1) total_out[0] = sh[t];
}

__global__ __launch_bounds__(256) void k_scan3(int* __restrict__ out, const int* __restrict__ bsum, int n){
  int add = bsum[blockIdx.x];
  int base = blockIdx.x * 2048 + threadIdx.x * 8;
#pragma unroll
  for (int i = 0; i < 8; ++i) if (base + i < n) out[base + i] += add;
}

// ---------------- fused: MFMA GEMM + light scatter + attention logits ----------------
#define GBM 64
#define GEMM_NB ((N_NODES + GBM - 1) / GBM)   // 1563
__global__ __launch_bounds__(256) void k_fused(const float* __restrict__ x,
                                               const __half* __restrict__ WpT, const float* __restrict__ bp,
                                               __half* __restrict__ h16,
                                               const int* __restrict__ eA, const int* __restrict__ eC,
                                               const int* __restrict__ eP,
                                               const int* __restrict__ gscan, int* __restrict__ packed,
                                               const float* __restrict__ wvec, const float* __restrict__ cbias,
                                               float* __restrict__ a_src, float* __restrict__ a_dst,
                                               unsigned* __restrict__ gpart){
  union U {
    _Float16 xs[64 * 256];
    int pos[NBUCK];
    struct { float wv[12][256]; float cb[12]; unsigned samax[6]; } att;
  };
  __shared__ U sm;
  int t = threadIdx.x;
  if (blockIdx.x >= GEMM_NB + NB1){
    // -------- attention-logits path --------
    int abi = blockIdx.x - (GEMM_NB + NB1);
#pragma unroll
    for (int q = 0; q < 12; ++q) sm.att.wv[q][t] = wvec[q * NF + t];
    if (t < 12) sm.att.cb[t] = cbias[t];
    if (t < 6) sm.att.samax[t] = 0u;
    __syncthreads();
    int grp = t >> 4, lid = t & 15;
    int n = abi * 16 + grp;             // grid exact
    float4 xr[4];
#pragma unroll
    for (int k = 0; k < 4; ++k)
      xr[k] = *(const float4*)(x + (size_t)n * NF + k * 64 + lid * 4);
    float res[12];
#pragma unroll
    for (int q = 0; q < 12; ++q){
      float acc = 0.f;
#pragma unroll
      for (int k = 0; k < 4; ++k){
        float4 wq = *(const float4*)&sm.att.wv[q][k * 64 + lid * 4];
        acc += xr[k].x * wq.x + xr[k].y * wq.y + xr[k].z * wq.z + xr[k].w * wq.w;
      }
      acc += __shfl_xor(acc, 1, 16);
      acc += __shfl_xor(acc, 2, 16);
      acc += __shfl_xor(acc, 4, 16);
      acc += __shfl_xor(acc, 8, 16);
      res[q] = acc + sm.att.cb[q];
    }
    if (lid == 0){
#pragma unroll
      for (int v = 0; v < 3; ++v){
        int g = v * N_NODES + n;
        *(float2*)(a_src + (size_t)g * 2) = make_float2(res[v*2+0], res[v*2+1]);
        *(float2*)(a_dst + (size_t)g * 2) = make_float2(res[6+v*2+0], res[6+v*2+1]);
        atomicMax(&sm.att.samax[v*2+0], fenc(res[v*2+0]));
        atomicMax(&sm.att.samax[v*2+1], fenc(res[v*2+1]));
      }
    }
    __syncthreads();
    if (t < 6) gpart[abi * 6 + t] = sm.att.samax[t];
    return;
  }
  if (blockIdx.x >= GEMM_NB){
    // -------- scatter path: LDS cursors, index-only --------
    int bi = blockIdx.x - GEMM_NB;
    for (int b = t; b < NBUCK; b += 256) sm.pos[b] = gscan[b * NB1 + bi];
    __syncthreads();
    int base = bi * ECHUNK + t;
#pragma unroll
    for (int k = 0; k < EGRAIN; ++k){
      int i = base + k * 256;
      if (i < NE3){
        int v = i / ETOT; int j = i - v * ETOT;
        const int* ei = (v == 0) ? eA : (v == 1) ? eC : eP;
        int s, d;
        if (j < N_EDGES){ s = ei[j]; d = ei[N_EDGES + j]; } else { s = j - N_EDGES; d = s; }
        int vd = v * N_NODES + d;
        int p = atomicAdd(&sm.pos[vd >> 9], 1);
        packed[p] = s | ((vd & 511) << 17);
      }
    }
    return;
  }
  // -------- MFMA GEMM path: tile 64 x 192, K=256 --------
  int m0 = blockIdx.x * GBM;
#pragma unroll
  for (int k = 0; k < 8; ++k){
    int G = t + k * 256;            // granule id 0..2047 (16B each)
    int row = G >> 5, g = G & 31;
    int grow = m0 + row; if (grow >= N_NODES) grow = N_NODES - 1;
    const float4* src = (const float4*)(x + (size_t)grow * NF + ((g ^ (row & 7)) << 3));
    float4 lo = src[0], hi = src[1];
    f16x8 h;
    h[0]=(_Float16)lo.x; h[1]=(_Float16)lo.y; h[2]=(_Float16)lo.z; h[3]=(_Float16)lo.w;
    h[4]=(_Float16)hi.x; h[5]=(_Float16)hi.y; h[6]=(_Float16)hi.z; h[7]=(_Float16)hi.w;
    *(f16x8*)&sm.xs[(size_t)G << 3] = h;
  }
  __syncthreads();
  int lane = t & 63, w = t >> 6;
  int lr = lane & 15, lk = lane >> 4;
  int colb = w * 48;                  // wave's 48 output cols
  f32x4 acc[4][3];
#pragma unroll
  for (int mt = 0; mt < 4; ++mt)
#pragma unroll
    for (int ct = 0; ct < 3; ++ct) acc[mt][ct] = (f32x4){0.f, 0.f, 0.f, 0.f};
  float bpv[3];
#pragma unroll
  for (int ct = 0; ct < 3; ++ct) bpv[ct] = bp[colb + ct * 16 + lr];
#pragma unroll
  for (int kk = 0; kk < 8; ++kk){
    int khalf = kk * 32 + lk * 8;
    f16x8 av[4];
#pragma unroll
    for (int mt = 0; mt < 4; ++mt){
      int row = mt * 16 + lr;
      av[mt] = *(const f16x8*)&sm.xs[row * 256 + (khalf ^ ((row & 7) << 3))];
    }
    f16x8 bv[3];
#pragma unroll
    for (int ct = 0; ct < 3; ++ct){
      int col = colb + ct * 16 + lr;
      bv[ct] = *(const f16x8*)(const void*)(WpT + (size_t)col * NF + khalf);
    }
#pragma unroll
    for (int mt = 0; mt < 4; ++mt)
#pragma unroll
      for (int ct = 0; ct < 3; ++ct)
        acc[mt][ct] = __builtin_amdgcn_mfma_f32_16x16x32_f16(av[mt], bv[ct], acc[mt][ct], 0, 0, 0);
  }
#pragma unroll
  for (int mt = 0; mt < 4; ++mt){
#pragma unroll
    for (int r = 0; r < 4; ++r){
      int row = m0 + mt * 16 + lk * 4 + r;
      if (row < N_NODES){
#pragma unroll
        for (int ct = 0; ct < 3; ++ct)
          h16[(size_t)row * NOUT3 + colb + ct * 16 + lr] = __float2half(acc[mt][ct][r] + bpv[ct]);
      }
    }
  }
}

// ---------------- level-2: light permute; block 0 also reduces amax ----------------
__global__ __launch_bounds__(512) void k_build(const int* __restrict__ gscan, const int* __restrict__ packed,
                                               int* __restrict__ entries, int* __restrict__ offsets,
                                               const unsigned* __restrict__ gpart, unsigned* __restrict__ amax){
  __shared__ int hist2[512];
  __shared__ int sh[512];
  __shared__ unsigned smx[6];
  int b = blockIdx.x, t = threadIdx.x;
  if (b == 0){
    if (t < 6) smx[t] = 0u;
    __syncthreads();
    unsigned m[6] = {0u, 0u, 0u, 0u, 0u, 0u};
    for (int bi = t; bi < ATT2_NB; bi += 512){
      const unsigned* p = gpart + (size_t)bi * 6;
#pragma unroll
      for (int k = 0; k < 6; ++k) m[k] = max(m[k], p[k]);
    }
#pragma unroll
    for (int k = 0; k < 6; ++k) atomicMax(&smx[k], m[k]);
    __syncthreads();
    if (t < 6) amax[t] = smx[t];
  }
  int base = gscan[b * NB1];
  int end  = (b == NBUCK - 1) ? NE3 : gscan[(b + 1) * NB1];
  hist2[t] = 0;
  __syncthreads();
  for (int i = base + t; i < end; i += 512)
    atomicAdd(&hist2[(packed[i] >> 17) & 511], 1);
  __syncthreads();
  int cnt = hist2[t];
  sh[t] = cnt; __syncthreads();
  for (int off = 1; off < 512; off <<= 1){
    int xv = (t >= off) ? sh[t - off] : 0;
    __syncthreads();
    sh[t] += xv;
    __syncthreads();
  }
  int excl = sh[t] - cnt;
  hist2[t] = excl;                              // running cursor
  int vd0 = (b << 9) + t;
  if (vd0 < N3) offsets[vd0] = base + excl;
  if (b == NBUCK - 1 && t == 0) offsets[N3] = NE3;
  __syncthreads();
  for (int i = base + t; i < end; i += 512){
    int pk = packed[i];
    int low = (pk >> 17) & 511;
    int pos = atomicAdd(&hist2[low], 1);
    entries[base + pos] = pk & 0x1FFFF;
  }
}

// ---------------- gather: 16-lane groups, f32 p end-to-end (num/den consistent) ----------------
__global__ __launch_bounds__(256) void k_gather(const int* __restrict__ entries, const int* __restrict__ offsets,
                                                const float* __restrict__ a_src, const float* __restrict__ a_dst,
                                                const unsigned* __restrict__ amax,
                                                const __half* __restrict__ h16,
                                                const float* __restrict__ bA, const float* __restrict__ bC,
                                                const float* __restrict__ bP,
                                                const int* __restrict__ batch, unsigned* __restrict__ pooled){
  __shared__ unsigned red[64];
  __shared__ int kmin, kmax;
  int t = threadIdx.x;
  if (t == 0){ kmin = 0x7FFFFFFF; kmax = -1; }
  if (t < 64) red[t] = 0u;
  __syncthreads();
  int grp = t >> 4;
  int lid = t & 15;
  int g = blockIdx.x * 16 + grp;        // grid exact: N3/16 blocks
  int v = g / N_NODES; int n = g - v * N_NODES;
  int vN = v * N_NODES;
  float ad0 = a_dst[g*2+0], ad1 = a_dst[g*2+1];
  float m0 = lrelu(fdec(amax[v*2+0]) + ad0);   // >= max edge logit for this dst
  float m1 = lrelu(fdec(amax[v*2+1]) + ad1);
  int beg = offsets[g], end = offsets[g+1];
  int len = end - beg;
  float ax = 0.f, ay = 0.f, az = 0.f, aw = 0.f;
  float den0 = 0.f, den1 = 0.f;
  const char* hb = (const char*)h16;
  unsigned lconst = (unsigned)((v << 7) + (lid << 3));   // v*128 + lid*8 bytes
  for (int c0 = 0; c0 < len; c0 += 16){
    int nc = len - c0; if (nc > 16) nc = 16;
    // phase A: one edge per lane — coalesced entries read, exp pair (f32), byte offset
    unsigned off_ = 0u;
    float p0f = 0.f, p1f = 0.f;
    if (lid < nc){
      int s_ = entries[beg + c0 + lid];
      float2 ap = *(const float2*)(a_src + (size_t)(vN + s_) * 2);
      p0f = __expf(lrelu(ap.x + ad0) - m0);
      p1f = __expf(lrelu(ap.y + ad1) - m1);
      off_ = (unsigned)s_ * (NOUT3 * 2);
    }
    den0 += p0f; den1 += p1f;
    // phase B: broadcast byte-offset + f32 p, 8-deep load pipeline (lanes kk>=nc carry p=0)
    for (int k = 0; k < nc; k += 8){
      uint2 r[8]; float pa[8];
#pragma unroll
      for (int j = 0; j < 8; ++j){
        int kk = k + j;
        unsigned ob = (unsigned)__shfl((int)off_, kk, 16) + lconst;
        float pA = __shfl(p0f, kk, 16);
        float pB = __shfl(p1f, kk, 16);
        r[j] = *(const uint2*)(hb + ob);
        pa[j] = (lid < 8) ? pA : pB;
      }
#pragma unroll
      for (int j = 0; j < 8; ++j){
        float2 fa2 = __half22float2(*(__half2*)&r[j].x);
        float2 fb2 = __half22float2(*(__half2*)&r[j].y);
        ax = fmaf(pa[j], fa2.x, ax); ay = fmaf(pa[j], fa2.y, ay);
        az = fmaf(pa[j], fb2.x, az); aw = fmaf(pa[j], fb2.y, aw);
      }
    }
  }
#pragma unroll
  for (int msk = 1; msk < 16; msk <<= 1){
    den0 += __shfl_xor(den0, msk);
    den1 += __shfl_xor(den1, msk);
  }
  float den = ((lid < 8) ? den0 : den1) + 1e-16f;
  const float* bias = (v == 0) ? bA : (v == 1) ? bC : bP;
  float4 b4 = *(const float4*)(bias + lid * 4);
  unsigned e0u = fenc(eluf(ax / den + b4.x));
  unsigned e1u = fenc(eluf(ay / den + b4.y));
  unsigned e2u = fenc(eluf(az / den + b4.z));
  unsigned e3u = fenc(eluf(aw / den + b4.w));
  int key = v * NG + batch[n];
  if (lid == 0){ atomicMin(&kmin, key); atomicMax(&kmax, key); }
  atomicMax(&red[lid*4+0], e0u); atomicMax(&red[lid*4+1], e1u);
  atomicMax(&red[lid*4+2], e2u); atomicMax(&red[lid*4+3], e3u);
  __syncthreads();
  if (kmin == kmax){
    if (t < 64) atomicMax(&pooled[(size_t)kmin * 64 + t], red[t]);
  } else {
    unsigned* pp = pooled + (size_t)key * 64 + lid * 4;
    atomicMax(pp+0, e0u); atomicMax(pp+1, e1u); atomicMax(pp+2, e2u); atomicMax(pp+3, e3u);
  }
}

// ---------------- head MLP: one wave per graph ----------------
__global__ __launch_bounds__(64) void k_head(const unsigned* __restrict__ pooled,
                                             const float* __restrict__ g1w, const float* __restrict__ g1b,
                                             const float* __restrict__ g2w, const float* __restrict__ g2b,
                                             const float* __restrict__ c1w, const float* __restrict__ c1b,
                                             const float* __restrict__ c2w, const float* __restrict__ c2b,
                                             const float* __restrict__ c3w, const float* __restrict__ c3b,
                                             float* __restrict__ out){
  __shared__ float s1[64];
  __shared__ float s2[128];
  __shared__ float sw[3];
  int g = blockIdx.x, l = threadIdx.x;
  float ha = fdec(pooled[(size_t)g * 64 + l]);
  float hc = fdec(pooled[(size_t)(NG + g) * 64 + l]);
  float hp = fdec(pooled[(size_t)(2 * NG + g) * 64 + l]);
  s1[l] = (ha + hc + hp) * (1.f / 3.f);
  __syncthreads();
  float r1 = 0.f;
  if (l < 32){
    r1 = g1b[l];
    for (int i = 0; i < 64; ++i) r1 += s1[i] * g1w[i * 32 + l];
    r1 = fmaxf(r1, 0.f);
  }
  __syncthreads();
  if (l < 32) s2[l] = r1;
  __syncthreads();
  if (l < 3){
    float tv = g2b[l];
    for (int i = 0; i < 32; ++i) tv += s2[i] * g2w[i * 3 + l];
    sw[l] = tv;
  }
  __syncthreads();
  float t0 = sw[0], t1 = sw[1], t2 = sw[2];
  float mx = fmaxf(t0, fmaxf(t1, t2));
  float w0 = __expf(t0 - mx), w1 = __expf(t1 - mx), w2 = __expf(t2 - mx);
  float wsum = w0 + w1 + w2;
  float fused = (w0 * ha + w1 * hc + w2 * hp) / wsum;
  __syncthreads();
  s1[l] = fused;
  __syncthreads();
  float za = c1b[l], zb = c1b[64 + l];
  for (int i = 0; i < 64; ++i){
    float f = s1[i];
    za += f * c1w[i * 128 + l];
    zb += f * c1w[i * 128 + 64 + l];
  }
  za = fmaxf(za, 0.f); zb = fmaxf(zb, 0.f);
  s2[l] = za; s2[64 + l] = zb;
  __syncthreads();
  float z2 = c2b[l];
  for (int i = 0; i < 128; ++i) z2 += s2[i] * c2w[i * 64 + l];
  z2 = fmaxf(z2, 0.f);
  float prod = z2 * c3w[l];
  for (int off = 32; off > 0; off >>= 1) prod += __shfl_down(prod, off);
  if (l == 0) out[g] = prod + c3b[0];
}

extern "C" void kernel_launch(void* const* d_in, const int* in_sizes, int n_in,
                              void* d_out, int out_size, void* d_ws, size_t ws_size,
                              hipStream_t stream){
  const float* x    = (const float*)d_in[0];
  const int* eA     = (const int*)d_in[1];
  const int* eC     = (const int*)d_in[2];
  const int* eP     = (const int*)d_in[3];
  const int* batch  = (const int*)d_in[4];
  const float* bn_w = (const float*)d_in[6];
  const float* bn_b = (const float*)d_in[7];
  const float* WA   = (const float*)d_in[8];
  const float* asA  = (const float*)d_in[9];
  const float* adA  = (const float*)d_in[10];
  const float* bA   = (const float*)d_in[11];
  const float* WC   = (const float*)d_in[12];
  const float* asC  = (const float*)d_in[13];
  const float* adC  = (const float*)d_in[14];
  const float* bC   = (const float*)d_in[15];
  const float* WP   = (const float*)d_in[16];
  const float* asP  = (const float*)d_in[17];
  const float* adP  = (const float*)d_in[18];
  const float* bP   = (const float*)d_in[19];
  const float* g1w  = (const float*)d_in[20];
  const float* g1b  = (const float*)d_in[21];
  const float* g2w  = (const float*)d_in[22];
  const float* g2b  = (const float*)d_in[23];
  const float* c1w  = (const float*)d_in[24];
  const float* c1b  = (const float*)d_in[25];
  const float* c2w  = (const float*)d_in[26];
  const float* c2b  = (const float*)d_in[27];
  const float* c3w  = (const float*)d_in[28];
  const float* c3b  = (const float*)d_in[29];
  float* out = (float*)d_out;

  char* wptr = (char*)d_ws;
  auto alloc = [&](size_t bytes) -> void* {
    void* p = (void*)wptr;
    wptr += (bytes + 255) & ~(size_t)255;
    return p;
  };
  float*    sums    = (float*)   alloc((size_t)NF * 4);
  float*    sumsq   = (float*)   alloc((size_t)NF * 4);
  float*    spartS  = (float*)   alloc((size_t)NF * STATS_NB * 4);
  float*    spartQ  = (float*)   alloc((size_t)NF * STATS_NB * 4);
  int*      gcounts = (int*)     alloc((size_t)SCAN_N * 4);
  int*      gscan   = (int*)     alloc((size_t)SCAN_N * 4);
  int*      offsets = (int*)     alloc(((size_t)N3 + 1) * 4);
  __half*   WpT     = (__half*)  alloc((size_t)NOUT3 * NF * 2);
  float*    bp      = (float*)   alloc((size_t)NOUT3 * 4);
  float*    wvec    = (float*)   alloc((size_t)12 * NF * 4);
  float*    cbias   = (float*)   alloc((size_t)64 * 4);
  __half*   h16     = (__half*)  alloc((size_t)N_NODES * NOUT3 * 2);
  float*    a_src   = (float*)   alloc((size_t)N3 * 2 * 4);
  float*    a_dst   = (float*)   alloc((size_t)N3 * 2 * 4);
  int*      packed  = (int*)     alloc((size_t)NE3 * 4);
  int*      entries = (int*)     alloc((size_t)NE3 * 4);
  unsigned* pooled  = (unsigned*)alloc((size_t)3 * NG * NHC * 4);
  unsigned* gpart   = (unsigned*)alloc((size_t)ATT2_NB * 6 * 4);
  unsigned* amax    = (unsigned*)alloc((size_t)64 * 4);
  int*      bsum    = (int*)     alloc((size_t)512 * 4);
  int*      scrtot  = (int*)     alloc((size_t)64 * 4);

  k_init_pooled<<<(3 * NG * NHC + 255) / 256, 256, 0, stream>>>(pooled);
  k_pre<<<STATS_NB + NB1, 256, 0, stream>>>(x, spartS, spartQ, eA, eC, eP, gcounts);
  k_stats2<<<NF, 256, 0, stream>>>(spartS, spartQ, sums, sumsq);
  k_prep2<<<NOUT3 + 1, 256, 0, stream>>>(sums, sumsq, bn_w, bn_b,
                                         WA, asA, adA, WC, asC, adC, WP, asP, adP,
                                         WpT, bp, wvec, cbias);
  int nb_sc = (SCAN_N + 2047) / 2048;   // 293
  k_scan1<<<nb_sc, 256, 0, stream>>>(gcounts, gscan, bsum, SCAN_N);
  k_scan2<<<1, 512, 0, stream>>>(bsum, scrtot, nb_sc);
  k_scan3<<<nb_sc, 256, 0, stream>>>(gscan, bsum, SCAN_N);
  k_fused<<<GEMM_NB + NB1 + ATT2_NB, 256, 0, stream>>>(x, WpT, bp, h16, eA, eC, eP,
                                                       gscan, packed, wvec, cbias,
                                                       a_src, a_dst, gpart);
  k_build<<<NBUCK, 512, 0, stream>>>(gscan, packed, entries, offsets, gpart, amax);
  k_gather<<<N3 / 16, 256, 0, stream>>>(entries, offsets, a_src, a_dst, amax, h16, bA, bC, bP, batch, pooled);
  k_head<<<NG, 64, 0, stream>>>(pooled, g1w, g1b, g2w, g2b, c1w, c1b, c2w, c2b, c3w, c3b, out);
}

// Round 13
// 330.216 us; speedup vs baseline: 1.5469x; 1.1510x over previous
//
#include <hip/hip_runtime.h>
#include <hip/hip_bf16.h>
#include <hip/hip_fp16.h>

#define N_NODES 100000
#define N_EDGES 1600000
#define ETOT    (N_EDGES + N_NODES)   // 1,700,000
#define NE3     (3 * ETOT)            // 5,100,000
#define N3      (3 * N_NODES)         // 300,000
#define NF      256
#define NG      512
#define NHC     64
#define NOUT3   192
#define BN_EPS  1e-5f

// bucket sort params: 1024-node buckets
#define NBUCK   293                   // ceil(300000/1024)
#define NB1     1024                  // level-1 blocks
#define EGRAIN  20
#define ECHUNK  (256 * EGRAIN)        // 5120
#define SCAN_N  (NBUCK * NB1)         // 300032
#define ATT_NB  (N3 * 16 / 256)       // 18750

typedef _Float16 f16x8 __attribute__((ext_vector_type(8)));
typedef float    f32x4 __attribute__((ext_vector_type(4)));

__device__ __forceinline__ unsigned fenc(float f){
  unsigned b = __float_as_uint(f);
  return (b & 0x80000000u) ? ~b : (b | 0x80000000u);
}
__device__ __forceinline__ float fdec(unsigned u){
  unsigned b = (u & 0x80000000u) ? (u & 0x7FFFFFFFu) : ~u;
  return __uint_as_float(b);
}
__device__ __forceinline__ float lrelu(float x){ return x > 0.f ? x : 0.2f * x; }
__device__ __forceinline__ float eluf(float x){ return x > 0.f ? x : (__expf(x) - 1.f); }

// ---------------- init pooled to encoded -inf ----------------
__global__ void k_init_pooled(unsigned* pooled){
  int i = blockIdx.x * 256 + threadIdx.x;
  if (i < 3 * NG * NHC) pooled[i] = 0x007FFFFFu;   // fenc(-inf)
}

// ---------------- fused: column-stat partials (deterministic) + level-1 edge histogram ----------------
#define STATS_NB ((N_NODES + 127) / 128)    // 782
__global__ __launch_bounds__(256) void k_pre(const float* __restrict__ x,
                                             float* __restrict__ spartS, float* __restrict__ spartQ,
                                             const int* __restrict__ eA, const int* __restrict__ eC,
                                             const int* __restrict__ eP,
                                             int* __restrict__ gcounts){
  int t = threadIdx.x;
  if (blockIdx.x < STATS_NB){
    int r0 = blockIdx.x * 128;
    int rmax = N_NODES - r0; if (rmax > 128) rmax = 128;
    float s = 0.f, q = 0.f;
    for (int r = 0; r < rmax; ++r){
      float v = x[(size_t)(r0 + r) * NF + t];
      s += v; q += v * v;
    }
    spartS[(size_t)t * STATS_NB + blockIdx.x] = s;   // plain stores, no atomics
    spartQ[(size_t)t * STATS_NB + blockIdx.x] = q;
    return;
  }
  __shared__ int hist[NBUCK];
  int bi = blockIdx.x - STATS_NB;
  for (int b = t; b < NBUCK; b += 256) hist[b] = 0;
  __syncthreads();
  int base = bi * ECHUNK + t;
#pragma unroll
  for (int k = 0; k < EGRAIN; ++k){
    int i = base + k * 256;
    if (i < NE3){
      int v = i / ETOT; int j = i - v * ETOT;
      const int* ei = (v == 0) ? eA : (v == 1) ? eC : eP;
      int d = (j < N_EDGES) ? ei[N_EDGES + j] : (j - N_EDGES);
      int vd = v * N_NODES + d;
      atomicAdd(&hist[vd >> 10], 1);
    }
  }
  __syncthreads();
  for (int b = t; b < NBUCK; b += 256) gcounts[b * NB1 + bi] = hist[b];
}

// ---------------- deterministic fixed-order reduction of column stats ----------------
__global__ __launch_bounds__(256) void k_stats2(const float* __restrict__ spartS, const float* __restrict__ spartQ,
                                                float* __restrict__ sums, float* __restrict__ sumsq){
  __shared__ float rs[256], rq[256];
  int c = blockIdx.x, i = threadIdx.x;
  float s = 0.f, q = 0.f;
  for (int b = i; b < STATS_NB; b += 256){
    s += spartS[(size_t)c * STATS_NB + b];
    q += spartQ[(size_t)c * STATS_NB + b];
  }
  rs[i] = s; rq[i] = q;
  __syncthreads();
  for (int off = 128; off > 0; off >>= 1){
    if (i < off){ rs[i] += rs[i + off]; rq[i] += rq[i + off]; }
    __syncthreads();
  }
  if (i == 0){ sums[c] = rs[0]; sumsq[c] = rq[0]; }
}

// ---------------- fold BN into W'^T (fp16, [192][256]) and bias b' ----------------
__global__ __launch_bounds__(256) void k_prep2(const float* __restrict__ sums, const float* __restrict__ sumsq,
                                               const float* __restrict__ bn_w, const float* __restrict__ bn_b,
                                               const float* __restrict__ WA, const float* __restrict__ WC,
                                               const float* __restrict__ WP,
                                               __half* __restrict__ WpT, float* __restrict__ bp){
  __shared__ float red[256];
  int o = blockIdx.x;                 // 0..191
  int v = o >> 6, oc = o & 63;
  const float* W = (v == 0) ? WA : (v == 1) ? WC : WP;
  int f = threadIdx.x;
  float mu  = sums[f]  * (1.f / N_NODES);
  float var = sumsq[f] * (1.f / N_NODES) - mu * mu;
  float sc  = bn_w[f] * rsqrtf(var + BN_EPS);
  float sh_ = bn_b[f] - mu * sc;
  float w = W[f * 64 + oc];
  WpT[(size_t)o * NF + f] = __float2half(w * sc);
  red[f] = sh_ * w;
  __syncthreads();
  for (int off = 128; off > 0; off >>= 1){
    if (f < off) red[f] += red[f + off];
    __syncthreads();
  }
  if (f == 0) bp[o] = red[0];
}

// ---------------- exclusive scan (grain 8, 3 phases) ----------------
__global__ __launch_bounds__(256) void k_scan1(const int* __restrict__ cnt, int* __restrict__ out,
                                               int* __restrict__ bsum, int n){
  __shared__ int sh[256];
  int t = threadIdx.x; int base = blockIdx.x * 2048 + t * 8;
  int v[8]; int s = 0;
#pragma unroll
  for (int i = 0; i < 8; ++i){ v[i] = (base + i < n) ? cnt[base + i] : 0; s += v[i]; }
  sh[t] = s; __syncthreads();
  for (int off = 1; off < 256; off <<= 1){
    int xv = (t >= off) ? sh[t - off] : 0;
    __syncthreads();
    sh[t] += xv;
    __syncthreads();
  }
  int p = sh[t] - s;
  if (t == 255) bsum[blockIdx.x] = sh[255];
#pragma unroll
  for (int i = 0; i < 8; ++i){ if (base + i < n) out[base + i] = p; p += v[i]; }
}

__global__ __launch_bounds__(512) void k_scan2(int* __restrict__ bsum, int* __restrict__ total_out, int nb){
  __shared__ int sh[512];
  int t = threadIdx.x;
  int o = (t < nb) ? bsum[t] : 0;
  sh[t] = o; __syncthreads();
  for (int off = 1; off < 512; off <<= 1){
    int xv = (t >= off) ? sh[t - off] : 0;
    __syncthreads();
    sh[t] += xv;
    __syncthreads();
  }
  if (t < nb) bsum[t] = sh[t] - o;
  if (t == nb - 1) total_out[0] = sh[t];
}

__global__ __launch_bounds__(256) void k_scan3(int* __restrict__ out, const int* __restrict__ bsum, int n){
  int add = bsum[blockIdx.x];
  int base = blockIdx.x * 2048 + threadIdx.x * 8;
#pragma unroll
  for (int i = 0; i < 8; ++i) if (base + i < n) out[base + i] += add;
}

// ---------------- fused: MFMA fp16 GEMM + light level-1 scatter (index-only) ----------------
#define GBM 64
#define GEMM_NB ((N_NODES + GBM - 1) / GBM)   // 1563
__global__ __launch_bounds__(256) void k_fused(const float* __restrict__ x,
                                               const __half* __restrict__ WpT, const float* __restrict__ bp,
                                               __half* __restrict__ h16,
                                               const int* __restrict__ eA, const int* __restrict__ eC,
                                               const int* __restrict__ eP,
                                               const int* __restrict__ gscan, int* __restrict__ packed){
  union U { _Float16 xs[64 * 256]; int pos[NBUCK]; };
  __shared__ U sm;
  int t = threadIdx.x;
  if (blockIdx.x >= GEMM_NB){
    // -------- scatter path: LDS cursors, index-only --------
    int bi = blockIdx.x - GEMM_NB;
    for (int b = t; b < NBUCK; b += 256) sm.pos[b] = gscan[b * NB1 + bi];
    __syncthreads();
    int base = bi * ECHUNK + t;
#pragma unroll
    for (int k = 0; k < EGRAIN; ++k){
      int i = base + k * 256;
      if (i < NE3){
        int v = i / ETOT; int j = i - v * ETOT;
        const int* ei = (v == 0) ? eA : (v == 1) ? eC : eP;
        int s, d;
        if (j < N_EDGES){ s = ei[j]; d = ei[N_EDGES + j]; } else { s = j - N_EDGES; d = s; }
        int vd = v * N_NODES + d;
        int p = atomicAdd(&sm.pos[vd >> 10], 1);
        packed[p] = s | ((vd & 1023) << 17);
      }
    }
    return;
  }
  // -------- MFMA GEMM path: tile 64 x 192, K=256 --------
  int m0 = blockIdx.x * GBM;
#pragma unroll
  for (int k = 0; k < 8; ++k){
    int G = t + k * 256;            // granule id 0..2047 (16B each)
    int row = G >> 5, g = G & 31;
    int grow = m0 + row; if (grow >= N_NODES) grow = N_NODES - 1;
    const float4* src = (const float4*)(x + (size_t)grow * NF + ((g ^ (row & 7)) << 3));
    float4 lo = src[0], hi = src[1];
    f16x8 h;
    h[0]=(_Float16)lo.x; h[1]=(_Float16)lo.y; h[2]=(_Float16)lo.z; h[3]=(_Float16)lo.w;
    h[4]=(_Float16)hi.x; h[5]=(_Float16)hi.y; h[6]=(_Float16)hi.z; h[7]=(_Float16)hi.w;
    *(f16x8*)&sm.xs[(size_t)G << 3] = h;
  }
  __syncthreads();
  int lane = t & 63, w = t >> 6;
  int lr = lane & 15, lk = lane >> 4;
  int colb = w * 48;                  // wave's 48 output cols
  f32x4 acc[4][3];
#pragma unroll
  for (int mt = 0; mt < 4; ++mt)
#pragma unroll
    for (int ct = 0; ct < 3; ++ct) acc[mt][ct] = (f32x4){0.f, 0.f, 0.f, 0.f};
  float bpv[3];
#pragma unroll
  for (int ct = 0; ct < 3; ++ct) bpv[ct] = bp[colb + ct * 16 + lr];
#pragma unroll
  for (int kk = 0; kk < 8; ++kk){
    int khalf = kk * 32 + lk * 8;
    f16x8 av[4];
#pragma unroll
    for (int mt = 0; mt < 4; ++mt){
      int row = mt * 16 + lr;
      av[mt] = *(const f16x8*)&sm.xs[row * 256 + (khalf ^ ((row & 7) << 3))];
    }
    f16x8 bv[3];
#pragma unroll
    for (int ct = 0; ct < 3; ++ct){
      int col = colb + ct * 16 + lr;
      bv[ct] = *(const f16x8*)(const void*)(WpT + (size_t)col * NF + khalf);
    }
#pragma unroll
    for (int mt = 0; mt < 4; ++mt)
#pragma unroll
      for (int ct = 0; ct < 3; ++ct)
        acc[mt][ct] = __builtin_amdgcn_mfma_f32_16x16x32_f16(av[mt], bv[ct], acc[mt][ct], 0, 0, 0);
  }
#pragma unroll
  for (int mt = 0; mt < 4; ++mt){
#pragma unroll
    for (int r = 0; r < 4; ++r){
      int row = m0 + mt * 16 + lk * 4 + r;
      if (row < N_NODES){
#pragma unroll
        for (int ct = 0; ct < 3; ++ct)
          h16[(size_t)row * NOUT3 + colb + ct * 16 + lr] = __float2half(acc[mt][ct][r] + bpv[ct]);
      }
    }
  }
}

// ---------------- attention logits from h16 + per-block partial src-max (plain stores) ----------------
__global__ __launch_bounds__(256) void k_att(const __half* __restrict__ h16,
                                             const float* __restrict__ asA, const float* __restrict__ adA,
                                             const float* __restrict__ asC, const float* __restrict__ adC,
                                             const float* __restrict__ asP, const float* __restrict__ adP,
                                             float* __restrict__ a_src, float* __restrict__ a_dst,
                                             unsigned* __restrict__ gpart){
  __shared__ unsigned samax[6];
  int t = threadIdx.x;
  if (t < 6) samax[t] = 0u;
  __syncthreads();
  int gt = blockIdx.x * 256 + t;
  int g = gt >> 4; int lid = gt & 15;          // grid exact: g < N3 always
  int v = g / N_NODES; int n = g - v * N_NODES;
  const float* As = (v == 0) ? asA : (v == 1) ? asC : asP;
  const float* Ad = (v == 0) ? adA : (v == 1) ? adC : adP;
  const __half2* hp = (const __half2*)(h16 + (size_t)n * NOUT3 + v * 64 + lid * 4);
  float2 fa = __half22float2(hp[0]);
  float2 fb = __half22float2(hp[1]);
  float4 s4 = *(const float4*)(As + lid * 4);
  float4 d4 = *(const float4*)(Ad + lid * 4);
  float rs = fa.x*s4.x + fa.y*s4.y + fb.x*s4.z + fb.y*s4.w;
  float rd = fa.x*d4.x + fa.y*d4.y + fb.x*d4.z + fb.y*d4.w;
  rs += __shfl_xor(rs, 1); rd += __shfl_xor(rd, 1);
  rs += __shfl_xor(rs, 2); rd += __shfl_xor(rd, 2);
  rs += __shfl_xor(rs, 4); rd += __shfl_xor(rd, 4);
  if ((lid & 7) == 0){
    int h = lid >> 3;
    a_src[g * 2 + h] = rs;
    a_dst[g * 2 + h] = rd;
    atomicMax(&samax[v * 2 + h], fenc(rs));
  }
  __syncthreads();
  if (t < 6) gpart[blockIdx.x * 6 + t] = samax[t];   // plain store, no global atomic
}

// ---------------- level-2: light permute (1024 bins, 512 thr); block 0 reduces amax ----------------
__global__ __launch_bounds__(512) void k_build(const int* __restrict__ gscan, const int* __restrict__ packed,
                                               int* __restrict__ entries, int* __restrict__ offsets,
                                               const unsigned* __restrict__ gpart, unsigned* __restrict__ amax){
  __shared__ int hist2[1024];
  __shared__ int sh[512];
  __shared__ unsigned smx[6];
  int b = blockIdx.x, t = threadIdx.x;
  if (b == 0){
    if (t < 6) smx[t] = 0u;
    __syncthreads();
    unsigned m[6] = {0u, 0u, 0u, 0u, 0u, 0u};
    for (int bi = t; bi < ATT_NB; bi += 512){
      const unsigned* p = gpart + (size_t)bi * 6;
#pragma unroll
      for (int k = 0; k < 6; ++k) m[k] = max(m[k], p[k]);
    }
#pragma unroll
    for (int k = 0; k < 6; ++k) atomicMax(&smx[k], m[k]);
    __syncthreads();
    if (t < 6) amax[t] = smx[t];
  }
  int base = gscan[b * NB1];
  int end  = (b == NBUCK - 1) ? NE3 : gscan[(b + 1) * NB1];
  hist2[t * 2] = 0; hist2[t * 2 + 1] = 0;
  __syncthreads();
  for (int i = base + t; i < end; i += 512)
    atomicAdd(&hist2[(packed[i] >> 17) & 1023], 1);
  __syncthreads();
  int s0 = hist2[t * 2], s1 = hist2[t * 2 + 1];
  int tot = s0 + s1;
  sh[t] = tot; __syncthreads();
  for (int off = 1; off < 512; off <<= 1){
    int xv = (t >= off) ? sh[t - off] : 0;
    __syncthreads();
    sh[t] += xv;
    __syncthreads();
  }
  int excl = sh[t] - tot;
  hist2[t * 2]     = excl;
  hist2[t * 2 + 1] = excl + s0;
  int vd0 = (b << 10) + t * 2;
  if (vd0 < N3)     offsets[vd0]     = base + excl;
  if (vd0 + 1 < N3) offsets[vd0 + 1] = base + excl + s0;
  if (b == NBUCK - 1 && t == 0) offsets[N3] = NE3;
  __syncthreads();
  for (int i = base + t; i < end; i += 512){
    int pk = packed[i];
    int low = (pk >> 17) & 1023;
    int pos = atomicAdd(&hist2[low], 1);
    entries[base + pos] = pk & 0x1FFFF;
  }
}

// ---------------- gather: 16-lane groups, f32 p end-to-end (num/den consistent) ----------------
__global__ __launch_bounds__(256) void k_gather(const int* __restrict__ entries, const int* __restrict__ offsets,
                                                const float* __restrict__ a_src, const float* __restrict__ a_dst,
                                                const unsigned* __restrict__ amax,
                                                const __half* __restrict__ h16,
                                                const float* __restrict__ bA, const float* __restrict__ bC,
                                                const float* __restrict__ bP,
                                                const int* __restrict__ batch, unsigned* __restrict__ pooled){
  __shared__ unsigned red[64];
  __shared__ int kmin, kmax;
  int t = threadIdx.x;
  if (t == 0){ kmin = 0x7FFFFFFF; kmax = -1; }
  if (t < 64) red[t] = 0u;
  __syncthreads();
  int grp = t >> 4;
  int lid = t & 15;
  int g = blockIdx.x * 16 + grp;        // grid exact: N3/16 blocks
  int v = g / N_NODES; int n = g - v * N_NODES;
  int vN = v * N_NODES;
  float ad0 = a_dst[g*2+0], ad1 = a_dst[g*2+1];
  float m0 = lrelu(fdec(amax[v*2+0]) + ad0);   // >= max edge logit for this dst
  float m1 = lrelu(fdec(amax[v*2+1]) + ad1);
  int beg = offsets[g], end = offsets[g+1];
  int len = end - beg;
  float ax = 0.f, ay = 0.f, az = 0.f, aw = 0.f;
  float den0 = 0.f, den1 = 0.f;
  const char* hb = (const char*)h16;
  unsigned lconst = (unsigned)((v << 7) + (lid << 3));   // v*128 + lid*8 bytes
  for (int c0 = 0; c0 < len; c0 += 16){
    int nc = len - c0; if (nc > 16) nc = 16;
    // phase A: one edge per lane — coalesced entries read, exp pair (f32), byte offset
    unsigned off_ = 0u;
    float p0f = 0.f, p1f = 0.f;
    if (lid < nc){
      int s_ = entries[beg + c0 + lid];
      float2 ap = *(const float2*)(a_src + (size_t)(vN + s_) * 2);
      p0f = __expf(lrelu(ap.x + ad0) - m0);
      p1f = __expf(lrelu(ap.y + ad1) - m1);
      off_ = (unsigned)s_ * (NOUT3 * 2);
    }
    den0 += p0f; den1 += p1f;
    // phase B: broadcast byte-offset + f32 p, 8-deep load pipeline (lanes kk>=nc carry p=0)
    for (int k = 0; k < nc; k += 8){
      uint2 r[8]; float pa[8];
#pragma unroll
      for (int j = 0; j < 8; ++j){
        int kk = k + j;
        unsigned ob = (unsigned)__shfl((int)off_, kk, 16) + lconst;
        float pA = __shfl(p0f, kk, 16);
        float pB = __shfl(p1f, kk, 16);
        r[j] = *(const uint2*)(hb + ob);
        pa[j] = (lid < 8) ? pA : pB;
      }
#pragma unroll
      for (int j = 0; j < 8; ++j){
        float2 fa2 = __half22float2(*(__half2*)&r[j].x);
        float2 fb2 = __half22float2(*(__half2*)&r[j].y);
        ax = fmaf(pa[j], fa2.x, ax); ay = fmaf(pa[j], fa2.y, ay);
        az = fmaf(pa[j], fb2.x, az); aw = fmaf(pa[j], fb2.y, aw);
      }
    }
  }
#pragma unroll
  for (int msk = 1; msk < 16; msk <<= 1){
    den0 += __shfl_xor(den0, msk);
    den1 += __shfl_xor(den1, msk);
  }
  float den = ((lid < 8) ? den0 : den1) + 1e-16f;
  const float* bias = (v == 0) ? bA : (v == 1) ? bC : bP;
  float4 b4 = *(const float4*)(bias + lid * 4);
  unsigned e0u = fenc(eluf(ax / den + b4.x));
  unsigned e1u = fenc(eluf(ay / den + b4.y));
  unsigned e2u = fenc(eluf(az / den + b4.z));
  unsigned e3u = fenc(eluf(aw / den + b4.w));
  int key = v * NG + batch[n];
  if (lid == 0){ atomicMin(&kmin, key); atomicMax(&kmax, key); }
  atomicMax(&red[lid*4+0], e0u); atomicMax(&red[lid*4+1], e1u);
  atomicMax(&red[lid*4+2], e2u); atomicMax(&red[lid*4+3], e3u);
  __syncthreads();
  if (kmin == kmax){
    if (t < 64) atomicMax(&pooled[(size_t)kmin * 64 + t], red[t]);
  } else {
    unsigned* pp = pooled + (size_t)key * 64 + lid * 4;
    atomicMax(pp+0, e0u); atomicMax(pp+1, e1u); atomicMax(pp+2, e2u); atomicMax(pp+3, e3u);
  }
}

// ---------------- head MLP: one wave per graph ----------------
__global__ __launch_bounds__(64) void k_head(const unsigned* __restrict__ pooled,
                                             const float* __restrict__ g1w, const float* __restrict__ g1b,
                                             const float* __restrict__ g2w, const float* __restrict__ g2b,
                                             const float* __restrict__ c1w, const float* __restrict__ c1b,
                                             const float* __restrict__ c2w, const float* __restrict__ c2b,
                                             const float* __restrict__ c3w, const float* __restrict__ c3b,
                                             float* __restrict__ out){
  __shared__ float s1[64];
  __shared__ float s2[128];
  __shared__ float sw[3];
  int g = blockIdx.x, l = threadIdx.x;
  float ha = fdec(pooled[(size_t)g * 64 + l]);
  float hc = fdec(pooled[(size_t)(NG + g) * 64 + l]);
  float hp = fdec(pooled[(size_t)(2 * NG + g) * 64 + l]);
  s1[l] = (ha + hc + hp) * (1.f / 3.f);
  __syncthreads();
  float r1 = 0.f;
  if (l < 32){
    r1 = g1b[l];
    for (int i = 0; i < 64; ++i) r1 += s1[i] * g1w[i * 32 + l];
    r1 = fmaxf(r1, 0.f);
  }
  __syncthreads();
  if (l < 32) s2[l] = r1;
  __syncthreads();
  if (l < 3){
    float tv = g2b[l];
    for (int i = 0; i < 32; ++i) tv += s2[i] * g2w[i * 3 + l];
    sw[l] = tv;
  }
  __syncthreads();
  float t0 = sw[0], t1 = sw[1], t2 = sw[2];
  float mx = fmaxf(t0, fmaxf(t1, t2));
  float w0 = __expf(t0 - mx), w1 = __expf(t1 - mx), w2 = __expf(t2 - mx);
  float wsum = w0 + w1 + w2;
  float fused = (w0 * ha + w1 * hc + w2 * hp) / wsum;
  __syncthreads();
  s1[l] = fused;
  __syncthreads();
  float za = c1b[l], zb = c1b[64 + l];
  for (int i = 0; i < 64; ++i){
    float f = s1[i];
    za += f * c1w[i * 128 + l];
    zb += f * c1w[i * 128 + 64 + l];
  }
  za = fmaxf(za, 0.f); zb = fmaxf(zb, 0.f);
  s2[l] = za; s2[64 + l] = zb;
  __syncthreads();
  float z2 = c2b[l];
  for (int i = 0; i < 128; ++i) z2 += s2[i] * c2w[i * 64 + l];
  z2 = fmaxf(z2, 0.f);
  float prod = z2 * c3w[l];
  for (int off = 32; off > 0; off >>= 1) prod += __shfl_down(prod, off);
  if (l == 0) out[g] = prod + c3b[0];
}

extern "C" void kernel_launch(void* const* d_in, const int* in_sizes, int n_in,
                              void* d_out, int out_size, void* d_ws, size_t ws_size,
                              hipStream_t stream){
  const float* x    = (const float*)d_in[0];
  const int* eA     = (const int*)d_in[1];
  const int* eC     = (const int*)d_in[2];
  const int* eP     = (const int*)d_in[3];
  const int* batch  = (const int*)d_in[4];
  const float* bn_w = (const float*)d_in[6];
  const float* bn_b = (const float*)d_in[7];
  const float* WA   = (const float*)d_in[8];
  const float* asA  = (const float*)d_in[9];
  const float* adA  = (const float*)d_in[10];
  const float* bA   = (const float*)d_in[11];
  const float* WC   = (const float*)d_in[12];
  const float* asC  = (const float*)d_in[13];
  const float* adC  = (const float*)d_in[14];
  const float* bC   = (const float*)d_in[15];
  const float* WP   = (const float*)d_in[16];
  const float* asP  = (const float*)d_in[17];
  const float* adP  = (const float*)d_in[18];
  const float* bP   = (const float*)d_in[19];
  const float* g1w  = (const float*)d_in[20];
  const float* g1b  = (const float*)d_in[21];
  const float* g2w  = (const float*)d_in[22];
  const float* g2b  = (const float*)d_in[23];
  const float* c1w  = (const float*)d_in[24];
  const float* c1b  = (const float*)d_in[25];
  const float* c2w  = (const float*)d_in[26];
  const float* c2b  = (const float*)d_in[27];
  const float* c3w  = (const float*)d_in[28];
  const float* c3b  = (const float*)d_in[29];
  float* out = (float*)d_out;

  char* wptr = (char*)d_ws;
  auto alloc = [&](size_t bytes) -> void* {
    void* p = (void*)wptr;
    wptr += (bytes + 255) & ~(size_t)255;
    return p;
  };
  float*    sums    = (float*)   alloc((size_t)NF * 4);
  float*    sumsq   = (float*)   alloc((size_t)NF * 4);
  float*    spartS  = (float*)   alloc((size_t)NF * STATS_NB * 4);
  float*    spartQ  = (float*)   alloc((size_t)NF * STATS_NB * 4);
  int*      gcounts = (int*)     alloc((size_t)SCAN_N * 4);
  int*      gscan   = (int*)     alloc((size_t)SCAN_N * 4);
  int*      offsets = (int*)     alloc(((size_t)N3 + 1) * 4);
  __half*   WpT     = (__half*)  alloc((size_t)NOUT3 * NF * 2);
  float*    bp      = (float*)   alloc((size_t)NOUT3 * 4);
  __half*   h16     = (__half*)  alloc((size_t)N_NODES * NOUT3 * 2);
  float*    a_src   = (float*)   alloc((size_t)N3 * 2 * 4);
  float*    a_dst   = (float*)   alloc((size_t)N3 * 2 * 4);
  int*      packed  = (int*)     alloc((size_t)NE3 * 4);
  int*      entries = (int*)     alloc((size_t)NE3 * 4);
  unsigned* pooled  = (unsigned*)alloc((size_t)3 * NG * NHC * 4);
  unsigned* gpart   = (unsigned*)alloc((size_t)ATT_NB * 6 * 4);
  unsigned* amax    = (unsigned*)alloc((size_t)64 * 4);
  int*      bsum    = (int*)     alloc((size_t)512 * 4);
  int*      scrtot  = (int*)     alloc((size_t)64 * 4);

  k_init_pooled<<<(3 * NG * NHC + 255) / 256, 256, 0, stream>>>(pooled);
  k_pre<<<STATS_NB + NB1, 256, 0, stream>>>(x, spartS, spartQ, eA, eC, eP, gcounts);
  k_stats2<<<NF, 256, 0, stream>>>(spartS, spartQ, sums, sumsq);
  k_prep2<<<NOUT3, 256, 0, stream>>>(sums, sumsq, bn_w, bn_b, WA, WC, WP, WpT, bp);
  int nb_sc = (SCAN_N + 2047) / 2048;   // 147
  k_scan1<<<nb_sc, 256, 0, stream>>>(gcounts, gscan, bsum, SCAN_N);
  k_scan2<<<1, 512, 0, stream>>>(bsum, scrtot, nb_sc);
  k_scan3<<<nb_sc, 256, 0, stream>>>(gscan, bsum, SCAN_N);
  k_fused<<<GEMM_NB + NB1, 256, 0, stream>>>(x, WpT, bp, h16, eA, eC, eP, gscan, packed);
  k_att<<<ATT_NB, 256, 0, stream>>>(h16, asA, adA, asC, adC, asP, adP, a_src, a_dst, gpart);
  k_build<<<NBUCK, 512, 0, stream>>>(gscan, packed, entries, offsets, gpart, amax);
  k_gather<<<N3 / 16, 256, 0, stream>>>(entries, offsets, a_src, a_dst, amax, h16, bA, bC, bP, batch, pooled);
  k_head<<<NG, 64, 0, stream>>>(pooled, g1w, g1b, g2w, g2b, c1w, c1b, c2w, c2b, c3w, c3b, out);
}

// Round 14
// 327.702 us; speedup vs baseline: 1.5588x; 1.0077x over previous
//
#include <hip/hip_runtime.h>
#include <hip/hip_bf16.h>
#include <hip/hip_fp16.h>

#define N_NODES 100000
#define N_EDGES 1600000
#define ETOT    (N_EDGES + N_NODES)   // 1,700,000
#define NE3     (3 * ETOT)            // 5,100,000
#define N3      (3 * N_NODES)         // 300,000
#define NF      256
#define NG      512
#define NHC     64
#define NOUT3   192
#define BN_EPS  1e-5f

// bucket sort params: 1024-node buckets
#define NBUCK   293                   // ceil(300000/1024)
#define NB1     1024                  // level-1 blocks
#define EGRAIN  20
#define ECHUNK  (256 * EGRAIN)        // 5120
#define SCAN_N  (NBUCK * NB1)         // 300032
#define ATT_NB  (N3 * 16 / 256)       // 18750
#define INIT_NB ((3 * NG * NHC + 255) / 256)  // 384

typedef _Float16 f16x8 __attribute__((ext_vector_type(8)));
typedef float    f32x4 __attribute__((ext_vector_type(4)));

__device__ __forceinline__ unsigned fenc(float f){
  unsigned b = __float_as_uint(f);
  return (b & 0x80000000u) ? ~b : (b | 0x80000000u);
}
__device__ __forceinline__ float fdec(unsigned u){
  unsigned b = (u & 0x80000000u) ? (u & 0x7FFFFFFFu) : ~u;
  return __uint_as_float(b);
}
__device__ __forceinline__ float lrelu(float x){ return x > 0.f ? x : 0.2f * x; }
__device__ __forceinline__ float eluf(float x){ return x > 0.f ? x : (__expf(x) - 1.f); }

// ---------------- fused: column-stat partials + level-1 edge histogram + pooled init ----------------
#define STATS_NB ((N_NODES + 127) / 128)    // 782
__global__ __launch_bounds__(256) void k_pre(const float* __restrict__ x,
                                             float* __restrict__ spartS, float* __restrict__ spartQ,
                                             const int* __restrict__ eA, const int* __restrict__ eC,
                                             const int* __restrict__ eP,
                                             int* __restrict__ gcounts, unsigned* __restrict__ pooled){
  int t = threadIdx.x;
  if (blockIdx.x >= STATS_NB + NB1){
    int i = (blockIdx.x - STATS_NB - NB1) * 256 + t;
    if (i < 3 * NG * NHC) pooled[i] = 0x007FFFFFu;   // fenc(-inf)
    return;
  }
  if (blockIdx.x < STATS_NB){
    int r0 = blockIdx.x * 128;
    int rmax = N_NODES - r0; if (rmax > 128) rmax = 128;
    float s = 0.f, q = 0.f;
    for (int r = 0; r < rmax; ++r){
      float v = x[(size_t)(r0 + r) * NF + t];
      s += v; q += v * v;
    }
    spartS[(size_t)t * STATS_NB + blockIdx.x] = s;   // plain stores, no atomics
    spartQ[(size_t)t * STATS_NB + blockIdx.x] = q;
    return;
  }
  __shared__ int hist[NBUCK];
  int bi = blockIdx.x - STATS_NB;
  for (int b = t; b < NBUCK; b += 256) hist[b] = 0;
  __syncthreads();
  int base = bi * ECHUNK + t;
#pragma unroll
  for (int k = 0; k < EGRAIN; ++k){
    int i = base + k * 256;
    if (i < NE3){
      int v = i / ETOT; int j = i - v * ETOT;
      const int* ei = (v == 0) ? eA : (v == 1) ? eC : eP;
      int d = (j < N_EDGES) ? ei[N_EDGES + j] : (j - N_EDGES);
      int vd = v * N_NODES + d;
      atomicAdd(&hist[vd >> 10], 1);
    }
  }
  __syncthreads();
  for (int b = t; b < NBUCK; b += 256) gcounts[b * NB1 + bi] = hist[b];
}

// ---------------- deterministic fixed-order reduction of column stats ----------------
__global__ __launch_bounds__(256) void k_stats2(const float* __restrict__ spartS, const float* __restrict__ spartQ,
                                                float* __restrict__ sums, float* __restrict__ sumsq){
  __shared__ float rs[256], rq[256];
  int c = blockIdx.x, i = threadIdx.x;
  float s = 0.f, q = 0.f;
  for (int b = i; b < STATS_NB; b += 256){
    s += spartS[(size_t)c * STATS_NB + b];
    q += spartQ[(size_t)c * STATS_NB + b];
  }
  rs[i] = s; rq[i] = q;
  __syncthreads();
  for (int off = 128; off > 0; off >>= 1){
    if (i < off){ rs[i] += rs[i + off]; rq[i] += rq[i + off]; }
    __syncthreads();
  }
  if (i == 0){ sums[c] = rs[0]; sumsq[c] = rq[0]; }
}

// ---------------- fold BN into W'^T (fp16, [192][256]) and bias b' ----------------
__global__ __launch_bounds__(256) void k_prep2(const float* __restrict__ sums, const float* __restrict__ sumsq,
                                               const float* __restrict__ bn_w, const float* __restrict__ bn_b,
                                               const float* __restrict__ WA, const float* __restrict__ WC,
                                               const float* __restrict__ WP,
                                               __half* __restrict__ WpT, float* __restrict__ bp){
  __shared__ float red[256];
  int o = blockIdx.x;                 // 0..191
  int v = o >> 6, oc = o & 63;
  const float* W = (v == 0) ? WA : (v == 1) ? WC : WP;
  int f = threadIdx.x;
  float mu  = sums[f]  * (1.f / N_NODES);
  float var = sumsq[f] * (1.f / N_NODES) - mu * mu;
  float sc  = bn_w[f] * rsqrtf(var + BN_EPS);
  float sh_ = bn_b[f] - mu * sc;
  float w = W[f * 64 + oc];
  WpT[(size_t)o * NF + f] = __float2half(w * sc);
  red[f] = sh_ * w;
  __syncthreads();
  for (int off = 128; off > 0; off >>= 1){
    if (f < off) red[f] += red[f + off];
    __syncthreads();
  }
  if (f == 0) bp[o] = red[0];
}

// ---------------- exclusive scan (grain 8, 3 phases) ----------------
__global__ __launch_bounds__(256) void k_scan1(const int* __restrict__ cnt, int* __restrict__ out,
                                               int* __restrict__ bsum, int n){
  __shared__ int sh[256];
  int t = threadIdx.x; int base = blockIdx.x * 2048 + t * 8;
  int v[8]; int s = 0;
#pragma unroll
  for (int i = 0; i < 8; ++i){ v[i] = (base + i < n) ? cnt[base + i] : 0; s += v[i]; }
  sh[t] = s; __syncthreads();
  for (int off = 1; off < 256; off <<= 1){
    int xv = (t >= off) ? sh[t - off] : 0;
    __syncthreads();
    sh[t] += xv;
    __syncthreads();
  }
  int p = sh[t] - s;
  if (t == 255) bsum[blockIdx.x] = sh[255];
#pragma unroll
  for (int i = 0; i < 8; ++i){ if (base + i < n) out[base + i] = p; p += v[i]; }
}

__global__ __launch_bounds__(512) void k_scan2(int* __restrict__ bsum, int* __restrict__ total_out, int nb){
  __shared__ int sh[512];
  int t = threadIdx.x;
  int o = (t < nb) ? bsum[t] : 0;
  sh[t] = o; __syncthreads();
  for (int off = 1; off < 512; off <<= 1){
    int xv = (t >= off) ? sh[t - off] : 0;
    __syncthreads();
    sh[t] += xv;
    __syncthreads();
  }
  if (t < nb) bsum[t] = sh[t] - o;
  if (t == nb - 1) total_out[0] = sh[t];
}

__global__ __launch_bounds__(256) void k_scan3(int* __restrict__ out, const int* __restrict__ bsum, int n){
  int add = bsum[blockIdx.x];
  int base = blockIdx.x * 2048 + threadIdx.x * 8;
#pragma unroll
  for (int i = 0; i < 8; ++i) if (base + i < n) out[base + i] += add;
}

// ---------------- fused: MFMA fp16 GEMM + light scatter, 3:2 block-interleaved ----------------
#define GBM 64
#define GEMM_NB ((N_NODES + GBM - 1) / GBM)   // 1563
#define NGRP5   521                           // ceil(GEMM_NB/3)=521, ceil(NB1/2)=512
#define FUSED_NB (NGRP5 * 5)                  // 2605
__global__ __launch_bounds__(256) void k_fused(const float* __restrict__ x,
                                               const __half* __restrict__ WpT, const float* __restrict__ bp,
                                               __half* __restrict__ h16,
                                               const int* __restrict__ eA, const int* __restrict__ eC,
                                               const int* __restrict__ eP,
                                               const int* __restrict__ gscan, int* __restrict__ packed){
  union U { _Float16 xs[64 * 256]; int pos[NBUCK]; };
  __shared__ U sm;
  int t = threadIdx.x;
  int grp5 = blockIdx.x / 5, rem5 = blockIdx.x % 5;
  if (rem5 >= 3){
    // -------- scatter path: LDS cursors, index-only --------
    int bi = grp5 * 2 + (rem5 - 3);
    if (bi >= NB1) return;
    for (int b = t; b < NBUCK; b += 256) sm.pos[b] = gscan[b * NB1 + bi];
    __syncthreads();
    int base = bi * ECHUNK + t;
#pragma unroll
    for (int k = 0; k < EGRAIN; ++k){
      int i = base + k * 256;
      if (i < NE3){
        int v = i / ETOT; int j = i - v * ETOT;
        const int* ei = (v == 0) ? eA : (v == 1) ? eC : eP;
        int s, d;
        if (j < N_EDGES){ s = ei[j]; d = ei[N_EDGES + j]; } else { s = j - N_EDGES; d = s; }
        int vd = v * N_NODES + d;
        int p = atomicAdd(&sm.pos[vd >> 10], 1);
        packed[p] = s | ((vd & 1023) << 17);
      }
    }
    return;
  }
  // -------- MFMA GEMM path: tile 64 x 192, K=256 --------
  int gb = grp5 * 3 + rem5;
  if (gb >= GEMM_NB) return;
  int m0 = gb * GBM;
#pragma unroll
  for (int k = 0; k < 8; ++k){
    int G = t + k * 256;            // granule id 0..2047 (16B each)
    int row = G >> 5, g = G & 31;
    int grow = m0 + row; if (grow >= N_NODES) grow = N_NODES - 1;
    const float4* src = (const float4*)(x + (size_t)grow * NF + ((g ^ (row & 7)) << 3));
    float4 lo = src[0], hi = src[1];
    f16x8 h;
    h[0]=(_Float16)lo.x; h[1]=(_Float16)lo.y; h[2]=(_Float16)lo.z; h[3]=(_Float16)lo.w;
    h[4]=(_Float16)hi.x; h[5]=(_Float16)hi.y; h[6]=(_Float16)hi.z; h[7]=(_Float16)hi.w;
    *(f16x8*)&sm.xs[(size_t)G << 3] = h;
  }
  __syncthreads();
  int lane = t & 63, w = t >> 6;
  int lr = lane & 15, lk = lane >> 4;
  int colb = w * 48;                  // wave's 48 output cols
  f32x4 acc[4][3];
#pragma unroll
  for (int mt = 0; mt < 4; ++mt)
#pragma unroll
    for (int ct = 0; ct < 3; ++ct) acc[mt][ct] = (f32x4){0.f, 0.f, 0.f, 0.f};
  float bpv[3];
#pragma unroll
  for (int ct = 0; ct < 3; ++ct) bpv[ct] = bp[colb + ct * 16 + lr];
#pragma unroll
  for (int kk = 0; kk < 8; ++kk){
    int khalf = kk * 32 + lk * 8;
    f16x8 av[4];
#pragma unroll
    for (int mt = 0; mt < 4; ++mt){
      int row = mt * 16 + lr;
      av[mt] = *(const f16x8*)&sm.xs[row * 256 + (khalf ^ ((row & 7) << 3))];
    }
    f16x8 bv[3];
#pragma unroll
    for (int ct = 0; ct < 3; ++ct){
      int col = colb + ct * 16 + lr;
      bv[ct] = *(const f16x8*)(const void*)(WpT + (size_t)col * NF + khalf);
    }
#pragma unroll
    for (int mt = 0; mt < 4; ++mt)
#pragma unroll
      for (int ct = 0; ct < 3; ++ct)
        acc[mt][ct] = __builtin_amdgcn_mfma_f32_16x16x32_f16(av[mt], bv[ct], acc[mt][ct], 0, 0, 0);
  }
#pragma unroll
  for (int mt = 0; mt < 4; ++mt){
#pragma unroll
    for (int r = 0; r < 4; ++r){
      int row = m0 + mt * 16 + lk * 4 + r;
      if (row < N_NODES){
#pragma unroll
        for (int ct = 0; ct < 3; ++ct)
          h16[(size_t)row * NOUT3 + colb + ct * 16 + lr] = __float2half(acc[mt][ct][r] + bpv[ct]);
      }
    }
  }
}

// ---------------- attention logits from h16 + per-block partial src-max (plain stores) ----------------
__global__ __launch_bounds__(256) void k_att(const __half* __restrict__ h16,
                                             const float* __restrict__ asA, const float* __restrict__ adA,
                                             const float* __restrict__ asC, const float* __restrict__ adC,
                                             const float* __restrict__ asP, const float* __restrict__ adP,
                                             float* __restrict__ a_src, float* __restrict__ a_dst,
                                             unsigned* __restrict__ gpart){
  __shared__ unsigned samax[6];
  int t = threadIdx.x;
  if (t < 6) samax[t] = 0u;
  __syncthreads();
  int gt = blockIdx.x * 256 + t;
  int g = gt >> 4; int lid = gt & 15;          // grid exact: g < N3 always
  int v = g / N_NODES; int n = g - v * N_NODES;
  const float* As = (v == 0) ? asA : (v == 1) ? asC : asP;
  const float* Ad = (v == 0) ? adA : (v == 1) ? adC : adP;
  const __half2* hp = (const __half2*)(h16 + (size_t)n * NOUT3 + v * 64 + lid * 4);
  float2 fa = __half22float2(hp[0]);
  float2 fb = __half22float2(hp[1]);
  float4 s4 = *(const float4*)(As + lid * 4);
  float4 d4 = *(const float4*)(Ad + lid * 4);
  float rs = fa.x*s4.x + fa.y*s4.y + fb.x*s4.z + fb.y*s4.w;
  float rd = fa.x*d4.x + fa.y*d4.y + fb.x*d4.z + fb.y*d4.w;
  rs += __shfl_xor(rs, 1); rd += __shfl_xor(rd, 1);
  rs += __shfl_xor(rs, 2); rd += __shfl_xor(rd, 2);
  rs += __shfl_xor(rs, 4); rd += __shfl_xor(rd, 4);
  if ((lid & 7) == 0){
    int h = lid >> 3;
    a_src[g * 2 + h] = rs;
    a_dst[g * 2 + h] = rd;
    atomicMax(&samax[v * 2 + h], fenc(rs));
  }
  __syncthreads();
  if (t < 6) gpart[blockIdx.x * 6 + t] = samax[t];   // plain store, no global atomic
}

// ---------------- level-2: light permute (1024 bins, 512 thr); block 0 reduces amax ----------------
__global__ __launch_bounds__(512) void k_build(const int* __restrict__ gscan, const int* __restrict__ packed,
                                               int* __restrict__ entries, int* __restrict__ offsets,
                                               const unsigned* __restrict__ gpart, unsigned* __restrict__ amax){
  __shared__ int hist2[1024];
  __shared__ int sh[512];
  __shared__ unsigned smx[6];
  int b = blockIdx.x, t = threadIdx.x;
  if (b == 0){
    if (t < 6) smx[t] = 0u;
    __syncthreads();
    unsigned m[6] = {0u, 0u, 0u, 0u, 0u, 0u};
    for (int bi = t; bi < ATT_NB; bi += 512){
      const unsigned* p = gpart + (size_t)bi * 6;
#pragma unroll
      for (int k = 0; k < 6; ++k) m[k] = max(m[k], p[k]);
    }
#pragma unroll
    for (int k = 0; k < 6; ++k) atomicMax(&smx[k], m[k]);
    __syncthreads();
    if (t < 6) amax[t] = smx[t];
  }
  int base = gscan[b * NB1];
  int end  = (b == NBUCK - 1) ? NE3 : gscan[(b + 1) * NB1];
  hist2[t * 2] = 0; hist2[t * 2 + 1] = 0;
  __syncthreads();
  for (int i = base + t; i < end; i += 512)
    atomicAdd(&hist2[(packed[i] >> 17) & 1023], 1);
  __syncthreads();
  int s0 = hist2[t * 2], s1 = hist2[t * 2 + 1];
  int tot = s0 + s1;
  sh[t] = tot; __syncthreads();
  for (int off = 1; off < 512; off <<= 1){
    int xv = (t >= off) ? sh[t - off] : 0;
    __syncthreads();
    sh[t] += xv;
    __syncthreads();
  }
  int excl = sh[t] - tot;
  hist2[t * 2]     = excl;
  hist2[t * 2 + 1] = excl + s0;
  int vd0 = (b << 10) + t * 2;
  if (vd0 < N3)     offsets[vd0]     = base + excl;
  if (vd0 + 1 < N3) offsets[vd0 + 1] = base + excl + s0;
  if (b == NBUCK - 1 && t == 0) offsets[N3] = NE3;
  __syncthreads();
  for (int i = base + t; i < end; i += 512){
    int pk = packed[i];
    int low = (pk >> 17) & 1023;
    int pos = atomicAdd(&hist2[low], 1);
    entries[base + pos] = pk & 0x1FFFF;
  }
}

// ---------------- gather: 16-lane groups, packed-f16 p (2 shfls/edge), 32-bit offsets ----------------
__global__ __launch_bounds__(256) void k_gather(const int* __restrict__ entries, const int* __restrict__ offsets,
                                                const float* __restrict__ a_src, const float* __restrict__ a_dst,
                                                const unsigned* __restrict__ amax,
                                                const __half* __restrict__ h16,
                                                const float* __restrict__ bA, const float* __restrict__ bC,
                                                const float* __restrict__ bP,
                                                const int* __restrict__ batch, unsigned* __restrict__ pooled){
  __shared__ unsigned red[64];
  __shared__ int kmin, kmax;
  int t = threadIdx.x;
  if (t == 0){ kmin = 0x7FFFFFFF; kmax = -1; }
  if (t < 64) red[t] = 0u;
  __syncthreads();
  int grp = t >> 4;
  int lid = t & 15;
  int g = blockIdx.x * 16 + grp;        // grid exact: N3/16 blocks
  int v = g / N_NODES; int n = g - v * N_NODES;
  int vN = v * N_NODES;
  float ad0 = a_dst[g*2+0], ad1 = a_dst[g*2+1];
  float m0 = lrelu(fdec(amax[v*2+0]) + ad0);   // >= max edge logit for this dst
  float m1 = lrelu(fdec(amax[v*2+1]) + ad1);
  int beg = offsets[g], end = offsets[g+1];
  int len = end - beg;
  float ax = 0.f, ay = 0.f, az = 0.f, aw = 0.f;
  float den0 = 0.f, den1 = 0.f;
  const char* hb = (const char*)h16;
  unsigned lconst = (unsigned)((v << 7) + (lid << 3));   // v*128 + lid*8 bytes
  for (int c0 = 0; c0 < len; c0 += 16){
    int nc = len - c0; if (nc > 16) nc = 16;
    // phase A: one edge per lane — coalesced entries read, exp pair, pack to f16 (num/den consistent)
    unsigned off_ = 0u, pu_ = 0u;
    if (lid < nc){
      int s_ = entries[beg + c0 + lid];
      float2 ap = *(const float2*)(a_src + (size_t)(vN + s_) * 2);
      float p0 = __expf(lrelu(ap.x + ad0) - m0);
      float p1 = __expf(lrelu(ap.y + ad1) - m1);
      pu_ = (unsigned)__half_as_ushort(__float2half(p0))
          | ((unsigned)__half_as_ushort(__float2half(p1)) << 16);
      off_ = (unsigned)s_ * (NOUT3 * 2);
    }
    den0 += __half2float(__ushort_as_half((unsigned short)(pu_ & 0xFFFFu)));
    den1 += __half2float(__ushort_as_half((unsigned short)(pu_ >> 16)));
    // phase B: broadcast byte-offset + packed p, 8-deep load pipeline (lanes kk>=nc carry p=0)
    for (int k = 0; k < nc; k += 8){
      uint2 r[8]; float pa[8];
#pragma unroll
      for (int j = 0; j < 8; ++j){
        int kk = k + j;
        unsigned ob = (unsigned)__shfl((int)off_, kk, 16) + lconst;
        unsigned pk_ = (unsigned)__shfl((int)pu_, kk, 16);
        r[j] = *(const uint2*)(hb + ob);
        unsigned sel = (lid < 8) ? (pk_ & 0xFFFFu) : (pk_ >> 16);
        pa[j] = __half2float(__ushort_as_half((unsigned short)sel));
      }
#pragma unroll
      for (int j = 0; j < 8; ++j){
        float2 fa2 = __half22float2(*(__half2*)&r[j].x);
        float2 fb2 = __half22float2(*(__half2*)&r[j].y);
        ax = fmaf(pa[j], fa2.x, ax); ay = fmaf(pa[j], fa2.y, ay);
        az = fmaf(pa[j], fb2.x, az); aw = fmaf(pa[j], fb2.y, aw);
      }
    }
  }
#pragma unroll
  for (int msk = 1; msk < 16; msk <<= 1){
    den0 += __shfl_xor(den0, msk);
    den1 += __shfl_xor(den1, msk);
  }
  float den = ((lid < 8) ? den0 : den1) + 1e-16f;
  const float* bias = (v == 0) ? bA : (v == 1) ? bC : bP;
  float4 b4 = *(const float4*)(bias + lid * 4);
  unsigned e0u = fenc(eluf(ax / den + b4.x));
  unsigned e1u = fenc(eluf(ay / den + b4.y));
  unsigned e2u = fenc(eluf(az / den + b4.z));
  unsigned e3u = fenc(eluf(aw / den + b4.w));
  int key = v * NG + batch[n];
  if (lid == 0){ atomicMin(&kmin, key); atomicMax(&kmax, key); }
  atomicMax(&red[lid*4+0], e0u); atomicMax(&red[lid*4+1], e1u);
  atomicMax(&red[lid*4+2], e2u); atomicMax(&red[lid*4+3], e3u);
  __syncthreads();
  if (kmin == kmax){
    if (t < 64) atomicMax(&pooled[(size_t)kmin * 64 + t], red[t]);
  } else {
    unsigned* pp = pooled + (size_t)key * 64 + lid * 4;
    atomicMax(pp+0, e0u); atomicMax(pp+1, e1u); atomicMax(pp+2, e2u); atomicMax(pp+3, e3u);
  }
}

// ---------------- head MLP: one wave per graph ----------------
__global__ __launch_bounds__(64) void k_head(const unsigned* __restrict__ pooled,
                                             const float* __restrict__ g1w, const float* __restrict__ g1b,
                                             const float* __restrict__ g2w, const float* __restrict__ g2b,
                                             const float* __restrict__ c1w, const float* __restrict__ c1b,
                                             const float* __restrict__ c2w, const float* __restrict__ c2b,
                                             const float* __restrict__ c3w, const float* __restrict__ c3b,
                                             float* __restrict__ out){
  __shared__ float s1[64];
  __shared__ float s2[128];
  __shared__ float sw[3];
  int g = blockIdx.x, l = threadIdx.x;
  float ha = fdec(pooled[(size_t)g * 64 + l]);
  float hc = fdec(pooled[(size_t)(NG + g) * 64 + l]);
  float hp = fdec(pooled[(size_t)(2 * NG + g) * 64 + l]);
  s1[l] = (ha + hc + hp) * (1.f / 3.f);
  __syncthreads();
  float r1 = 0.f;
  if (l < 32){
    r1 = g1b[l];
    for (int i = 0; i < 64; ++i) r1 += s1[i] * g1w[i * 32 + l];
    r1 = fmaxf(r1, 0.f);
  }
  __syncthreads();
  if (l < 32) s2[l] = r1;
  __syncthreads();
  if (l < 3){
    float tv = g2b[l];
    for (int i = 0; i < 32; ++i) tv += s2[i] * g2w[i * 3 + l];
    sw[l] = tv;
  }
  __syncthreads();
  float t0 = sw[0], t1 = sw[1], t2 = sw[2];
  float mx = fmaxf(t0, fmaxf(t1, t2));
  float w0 = __expf(t0 - mx), w1 = __expf(t1 - mx), w2 = __expf(t2 - mx);
  float wsum = w0 + w1 + w2;
  float fused = (w0 * ha + w1 * hc + w2 * hp) / wsum;
  __syncthreads();
  s1[l] = fused;
  __syncthreads();
  float za = c1b[l], zb = c1b[64 + l];
  for (int i = 0; i < 64; ++i){
    float f = s1[i];
    za += f * c1w[i * 128 + l];
    zb += f * c1w[i * 128 + 64 + l];
  }
  za = fmaxf(za, 0.f); zb = fmaxf(zb, 0.f);
  s2[l] = za; s2[64 + l] = zb;
  __syncthreads();
  float z2 = c2b[l];
  for (int i = 0; i < 128; ++i) z2 += s2[i] * c2w[i * 64 + l];
  z2 = fmaxf(z2, 0.f);
  float prod = z2 * c3w[l];
  for (int off = 32; off > 0; off >>= 1) prod += __shfl_down(prod, off);
  if (l == 0) out[g] = prod + c3b[0];
}

extern "C" void kernel_launch(void* const* d_in, const int* in_sizes, int n_in,
                              void* d_out, int out_size, void* d_ws, size_t ws_size,
                              hipStream_t stream){
  const float* x    = (const float*)d_in[0];
  const int* eA     = (const int*)d_in[1];
  const int* eC     = (const int*)d_in[2];
  const int* eP     = (const int*)d_in[3];
  const int* batch  = (const int*)d_in[4];
  const float* bn_w = (const float*)d_in[6];
  const float* bn_b = (const float*)d_in[7];
  const float* WA   = (const float*)d_in[8];
  const float* asA  = (const float*)d_in[9];
  const float* adA  = (const float*)d_in[10];
  const float* bA   = (const float*)d_in[11];
  const float* WC   = (const float*)d_in[12];
  const float* asC  = (const float*)d_in[13];
  const float* adC  = (const float*)d_in[14];
  const float* bC   = (const float*)d_in[15];
  const float* WP   = (const float*)d_in[16];
  const float* asP  = (const float*)d_in[17];
  const float* adP  = (const float*)d_in[18];
  const float* bP   = (const float*)d_in[19];
  const float* g1w  = (const float*)d_in[20];
  const float* g1b  = (const float*)d_in[21];
  const float* g2w  = (const float*)d_in[22];
  const float* g2b  = (const float*)d_in[23];
  const float* c1w  = (const float*)d_in[24];
  const float* c1b  = (const float*)d_in[25];
  const float* c2w  = (const float*)d_in[26];
  const float* c2b  = (const float*)d_in[27];
  const float* c3w  = (const float*)d_in[28];
  const float* c3b  = (const float*)d_in[29];
  float* out = (float*)d_out;

  char* wptr = (char*)d_ws;
  auto alloc = [&](size_t bytes) -> void* {
    void* p = (void*)wptr;
    wptr += (bytes + 255) & ~(size_t)255;
    return p;
  };
  float*    sums    = (float*)   alloc((size_t)NF * 4);
  float*    sumsq   = (float*)   alloc((size_t)NF * 4);
  float*    spartS  = (float*)   alloc((size_t)NF * STATS_NB * 4);
  float*    spartQ  = (float*)   alloc((size_t)NF * STATS_NB * 4);
  int*      gcounts = (int*)     alloc((size_t)SCAN_N * 4);
  int*      gscan   = (int*)     alloc((size_t)SCAN_N * 4);
  int*      offsets = (int*)     alloc(((size_t)N3 + 1) * 4);
  __half*   WpT     = (__half*)  alloc((size_t)NOUT3 * NF * 2);
  float*    bp      = (float*)   alloc((size_t)NOUT3 * 4);
  __half*   h16     = (__half*)  alloc((size_t)N_NODES * NOUT3 * 2);
  float*    a_src   = (float*)   alloc((size_t)N3 * 2 * 4);
  float*    a_dst   = (float*)   alloc((size_t)N3 * 2 * 4);
  int*      packed  = (int*)     alloc((size_t)NE3 * 4);
  int*      entries = (int*)     alloc((size_t)NE3 * 4);
  unsigned* pooled  = (unsigned*)alloc((size_t)3 * NG * NHC * 4);
  unsigned* gpart   = (unsigned*)alloc((size_t)ATT_NB * 6 * 4);
  unsigned* amax    = (unsigned*)alloc((size_t)64 * 4);
  int*      bsum    = (int*)     alloc((size_t)512 * 4);
  int*      scrtot  = (int*)     alloc((size_t)64 * 4);

  k_pre<<<STATS_NB + NB1 + INIT_NB, 256, 0, stream>>>(x, spartS, spartQ, eA, eC, eP, gcounts, pooled);
  k_stats2<<<NF, 256, 0, stream>>>(spartS, spartQ, sums, sumsq);
  k_prep2<<<NOUT3, 256, 0, stream>>>(sums, sumsq, bn_w, bn_b, WA, WC, WP, WpT, bp);
  int nb_sc = (SCAN_N + 2047) / 2048;   // 147
  k_scan1<<<nb_sc, 256, 0, stream>>>(gcounts, gscan, bsum, SCAN_N);
  k_scan2<<<1, 512, 0, stream>>>(bsum, scrtot, nb_sc);
  k_scan3<<<nb_sc, 256, 0, stream>>>(gscan, bsum, SCAN_N);
  k_fused<<<FUSED_NB, 256, 0, stream>>>(x, WpT, bp, h16, eA, eC, eP, gscan, packed);
  k_att<<<ATT_NB, 256, 0, stream>>>(h16, asA, adA, asC, adC, asP, adP, a_src, a_dst, gpart);
  k_build<<<NBUCK, 512, 0, stream>>>(gscan, packed, entries, offsets, gpart, amax);
  k_gather<<<N3 / 16, 256, 0, stream>>>(entries, offsets, a_src, a_dst, amax, h16, bA, bC, bP, batch, pooled);
  k_head<<<NG, 64, 0, stream>>>(pooled, g1w, g1b, g2w, g2b, c1w, c1b, c2w, c2b, c3w, c3b, out);
}